// Round 1
// baseline (218.664 us; speedup 1.0000x reference)
//
#include <hip/hip_runtime.h>
#include <stdint.h>

typedef unsigned short u16;
typedef unsigned int   u32;
typedef __attribute__((ext_vector_type(4))) float f32x4;
typedef __attribute__((ext_vector_type(8))) short s16x8;

__device__ __forceinline__ u16 f2bf(float f) {
  u32 u = __builtin_bit_cast(u32, f);
  u = (u + 0x7FFFu + ((u >> 16) & 1u)) >> 16;
  return (u16)u;
}

__device__ __forceinline__ void gload_lds16(const void* g, void* l) {
  __builtin_amdgcn_global_load_lds((const __attribute__((address_space(1))) void*)g,
                                   (__attribute__((address_space(3))) void*)l,
                                   16, 0, 0);
}

#define MFMA16(a, b, c) __builtin_amdgcn_mfma_f32_16x16x32_bf16((a), (b), (c), 0, 0, 0)

// ---------------- cast fp32 -> bf16 (query/key/value) ----------------
__global__ void k_cast(const float* __restrict__ q, const float* __restrict__ k,
                       const float* __restrict__ v,
                       u16* __restrict__ oq, u16* __restrict__ ok, u16* __restrict__ ov) {
  const int z = blockIdx.z;
  const float* src = (z == 0) ? q : (z == 1) ? k : v;
  u16* dst = (z == 0) ? oq : (z == 1) ? ok : ov;
  const int i = (blockIdx.x * 256 + threadIdx.x) * 4;
  const float4 f = *(const float4*)(src + i);
  ushort4 o4;
  o4.x = f2bf(f.x); o4.y = f2bf(f.y); o4.z = f2bf(f.z); o4.w = f2bf(f.w);
  *(ushort4*)(dst + i) = o4;
}

// ---------------- transpose+cast weights: W[K][N] fp32 -> Wt[N][K] bf16 ----------------
__global__ void k_transpose_w(const float* __restrict__ w0, const float* __restrict__ w1,
                              const float* __restrict__ w2, const float* __restrict__ w3,
                              u16* __restrict__ o0, u16* __restrict__ o1,
                              u16* __restrict__ o2, u16* __restrict__ o3) {
  __shared__ float t[64][65];
  const int z = blockIdx.z;
  const float* w = (z == 0) ? w0 : (z == 1) ? w1 : (z == 2) ? w2 : w3;
  u16* o = (z == 0) ? o0 : (z == 1) ? o1 : (z == 2) ? o2 : o3;
  const int k0 = blockIdx.x * 64;
  const int n0 = blockIdx.y * 64;
  const int tx = threadIdx.x & 63, ty = threadIdx.x >> 6;
#pragma unroll
  for (int i = 0; i < 16; ++i) {
    const int r = ty * 16 + i;
    t[r][tx] = w[(size_t)(k0 + r) * 1024 + n0 + tx];
  }
  __syncthreads();
#pragma unroll
  for (int i = 0; i < 16; ++i) {
    const int r = ty * 16 + i;
    o[(size_t)(n0 + r) * 1024 + k0 + tx] = f2bf(t[tx][r]);
  }
}

// ---------------- position-bias MLP on the 63x63 unique rel offsets ----------------
// tbl layout: [16 heads][3969]  (entry p = (dy+31)*63 + (dx+31))
__global__ void k_posbias(const float* __restrict__ w0, const float* __restrict__ b0,
                          const float* __restrict__ w1, const float* __restrict__ b1,
                          const float* __restrict__ w2, const float* __restrict__ b2,
                          float* __restrict__ tbl) {
  __shared__ float h0[16][256];
  __shared__ float h1[16][256];
  const int t = threadIdx.x;
  const int p0 = blockIdx.x * 16;
  {
    const float wy = w0[t], wx = w0[256 + t], bb = b0[t];
#pragma unroll
    for (int r = 0; r < 16; ++r) {
      int p = p0 + r; if (p > 3968) p = 3968;
      const float dy = (float)(p / 63 - 31);
      const float dx = (float)(p % 63 - 31);
      const float v = dy * wy + dx * wx + bb;
      h0[r][t] = v > 0.f ? v : 0.01f * v;
    }
  }
  __syncthreads();
  {
    float acc[16];
    const float bb = b1[t];
#pragma unroll
    for (int r = 0; r < 16; ++r) acc[r] = bb;
    for (int k = 0; k < 256; ++k) {
      const float w = w1[k * 256 + t];
#pragma unroll
      for (int r = 0; r < 16; ++r) acc[r] += h0[r][k] * w;
    }
#pragma unroll
    for (int r = 0; r < 16; ++r) {
      const float v = acc[r];
      h1[r][t] = v > 0.f ? v : 0.01f * v;
    }
  }
  __syncthreads();
  {
    const int r = t >> 4, hh = t & 15;
    float acc = b2[hh];
    for (int k = 0; k < 256; ++k) acc += h1[r][k] * w2[k * 16 + hh];
    const int p = p0 + r;
    if (p < 3969) tbl[hh * 3969 + p] = acc;
  }
}

// ---------------- bf16 GEMM, 128x128 tile, BK=64, m97 structure ----------------
// A [M][K] bf16 row-major, Bt [N][K] bf16 (i.e. B transposed). fp32 accum.
// MODE 0: out bf16 scattered to [b*16+h][s][d] (QKV heads layout), z picks A/Bt/bias/out.
// MODE 1: out fp32 row-major [M][N] (final projection), z == 0.
template <int MODE>
__global__ __launch_bounds__(256) void k_gemm(
    const u16* __restrict__ A0, const u16* __restrict__ A1, const u16* __restrict__ A2,
    const u16* __restrict__ B0, const u16* __restrict__ B1, const u16* __restrict__ B2,
    const float* __restrict__ c0, const float* __restrict__ c1, const float* __restrict__ c2,
    void* __restrict__ o0, void* __restrict__ o1, void* __restrict__ o2,
    int Mdim, int Ndim, int Kdim) {
  __shared__ u16 sA[128 * 64];
  __shared__ u16 sB[128 * 64];
  const int z = blockIdx.z;
  const u16* A  = (z == 0) ? A0 : (z == 1) ? A1 : A2;
  const u16* Bt = (z == 0) ? B0 : (z == 1) ? B1 : B2;
  const float* bias = (z == 0) ? c0 : (z == 1) ? c1 : c2;

  const int tid = threadIdx.x, lane = tid & 63, w = tid >> 6;
  const int wr = w >> 1, wc = w & 1;
  const int m0 = blockIdx.y * 128, n0 = blockIdx.x * 128;

  f32x4 acc[4][4] = {};

  const u16* aRow = A  + (size_t)(m0 + w * 32 + (lane >> 3)) * Kdim + (lane & 7) * 8;
  const u16* bRow = Bt + (size_t)(n0 + w * 32 + (lane >> 3)) * Kdim + (lane & 7) * 8;

  for (int kt = 0; kt < Kdim; kt += 64) {
    __syncthreads();
#pragma unroll
    for (int i = 0; i < 4; ++i)
      gload_lds16(aRow + (size_t)i * 8 * Kdim + kt, sA + (w * 32 + i * 8) * 64);
#pragma unroll
    for (int i = 0; i < 4; ++i)
      gload_lds16(bRow + (size_t)i * 8 * Kdim + kt, sB + (w * 32 + i * 8) * 64);
    __syncthreads();
#pragma unroll
    for (int ks = 0; ks < 2; ++ks) {
      s16x8 af[4], bf[4];
#pragma unroll
      for (int m = 0; m < 4; ++m)
        af[m] = *(const s16x8*)(sA + (wr * 64 + m * 16 + (lane & 15)) * 64 + ks * 32 + (lane >> 4) * 8);
#pragma unroll
      for (int n = 0; n < 4; ++n)
        bf[n] = *(const s16x8*)(sB + (wc * 64 + n * 16 + (lane & 15)) * 64 + ks * 32 + (lane >> 4) * 8);
#pragma unroll
      for (int m = 0; m < 4; ++m)
#pragma unroll
        for (int n = 0; n < 4; ++n)
          acc[m][n] = MFMA16(af[m], bf[n], acc[m][n]);
    }
  }

  if (MODE == 0) {
    u16* out = (u16*)((z == 0) ? o0 : (z == 1) ? o1 : o2);
#pragma unroll
    for (int m = 0; m < 4; ++m) {
      const int gm = m0 + wr * 64 + m * 16 + ((lane >> 4) << 2);
#pragma unroll
      for (int n = 0; n < 4; ++n) {
        const int gn = n0 + wc * 64 + n * 16 + (lane & 15);
        const float bv = bias[gn];
        const int hh = gn >> 6, dd = gn & 63;
#pragma unroll
        for (int r = 0; r < 4; ++r) {
          const int row = gm + r;
          const int batch = row >> 10, ss = row & 1023;
          out[(((size_t)(batch * 16 + hh)) * 1024 + ss) * 64 + dd] = f2bf(acc[m][n][r] + bv);
        }
      }
    }
  } else {
    float* out = (float*)o0;
#pragma unroll
    for (int m = 0; m < 4; ++m) {
      const int gm = m0 + wr * 64 + m * 16 + ((lane >> 4) << 2);
#pragma unroll
      for (int n = 0; n < 4; ++n) {
        const int gn = n0 + wc * 64 + n * 16 + (lane & 15);
        const float bv = bias[gn];
#pragma unroll
        for (int r = 0; r < 4; ++r)
          out[(size_t)(gm + r) * Ndim + gn] = acc[m][n][r] + bv;
      }
    }
  }
}

// ---------------- V [bh][s][d] -> Vt [bh][d][s] (bf16 tiled transpose) ----------------
__global__ void k_vt(const u16* __restrict__ Vb, u16* __restrict__ Vt) {
  __shared__ u32 t[64][65];
  const int bh = blockIdx.y, s0 = blockIdx.x * 64;
  const int tx = threadIdx.x & 63, ty = threadIdx.x >> 6;
  const u16* src = Vb + (size_t)bh * 65536;
  u16* dst = Vt + (size_t)bh * 65536;
#pragma unroll
  for (int i = 0; i < 16; ++i) {
    const int r = ty * 16 + i;
    t[r][tx] = src[(size_t)(s0 + r) * 64 + tx];
  }
  __syncthreads();
#pragma unroll
  for (int i = 0; i < 16; ++i) {
    const int r = ty * 16 + i;  // d index
    dst[(size_t)r * 1024 + s0 + tx] = (u16)t[tx][r];
  }
}

// ---------------- flash attention: 128 q-rows/WG, 64-kv tiles, bias from LDS table ----
__global__ __launch_bounds__(256) void k_attn(
    const u16* __restrict__ Qb,   // [64 bh][1024][64]
    const u16* __restrict__ Kb,   // [64 bh][1024][64]
    const u16* __restrict__ Vt,   // [64 bh][64][1024]
    const float* __restrict__ tbl,// [16][3969]
    u16* __restrict__ ctx) {      // [4096][1024]
  __shared__ u16 sK[64 * 72];
  __shared__ u16 sV[64 * 72];
  __shared__ u16 sP[128 * 72];
  __shared__ float sT[3969];
  const int tid = threadIdx.x, lane = tid & 63, w = tid >> 6;
  const int bh = blockIdx.y, h = bh & 15, b = bh >> 4;
  const int q0 = blockIdx.x * 128;
  const u16* Qp = Qb + (size_t)bh * (1024 * 64);
  const u16* Kp = Kb + (size_t)bh * (1024 * 64);
  const u16* Vp = Vt + (size_t)bh * (64 * 1024);

  for (int i = tid; i < 3969; i += 256) sT[i] = tbl[h * 3969 + i];

  s16x8 qf[2][2];
#pragma unroll
  for (int m = 0; m < 2; ++m)
#pragma unroll
    for (int ks = 0; ks < 2; ++ks)
      qf[m][ks] = *(const s16x8*)(Qp + (size_t)(q0 + w * 32 + m * 16 + (lane & 15)) * 64
                                  + ks * 32 + (lane >> 4) * 8);

  f32x4 accO[2][4] = {};
  float mrow[2][4], lrow[2][4];
#pragma unroll
  for (int m = 0; m < 2; ++m)
#pragma unroll
    for (int r = 0; r < 4; ++r) { mrow[m][r] = -1e30f; lrow[m][r] = 0.f; }

  for (int kv0 = 0; kv0 < 1024; kv0 += 64) {
    __syncthreads();
    {
      const int rr = tid >> 3, cc = (tid & 7) * 8;
#pragma unroll
      for (int i = 0; i < 2; ++i) {
        *(uint4*)(sK + (rr + i * 32) * 72 + cc) =
            *(const uint4*)(Kp + (size_t)(kv0 + rr + i * 32) * 64 + cc);
        *(uint4*)(sV + (rr + i * 32) * 72 + cc) =
            *(const uint4*)(Vp + (size_t)(rr + i * 32) * 1024 + kv0 + cc);
      }
    }
    __syncthreads();

    f32x4 sc[2][4] = {};
#pragma unroll
    for (int ks = 0; ks < 2; ++ks) {
      s16x8 kf[4];
#pragma unroll
      for (int n = 0; n < 4; ++n)
        kf[n] = *(const s16x8*)(sK + (n * 16 + (lane & 15)) * 72 + ks * 32 + (lane >> 4) * 8);
#pragma unroll
      for (int m = 0; m < 2; ++m)
#pragma unroll
        for (int n = 0; n < 4; ++n)
          sc[m][n] = MFMA16(qf[m][ks], kf[n], sc[m][n]);
    }

#pragma unroll
    for (int m = 0; m < 2; ++m) {
#pragma unroll
      for (int r = 0; r < 4; ++r) {
        const int qi = q0 + w * 32 + m * 16 + ((lane >> 4) << 2) + r;
        const int yi = qi >> 5, xi = qi & 31;
        float sv[4], mx = -1e30f;
#pragma unroll
        for (int n = 0; n < 4; ++n) {
          const int j = kv0 + n * 16 + (lane & 15);
          const int dy = yi - (j >> 5) + 31;
          const int dx = xi - (j & 31) + 31;
          const float val = sc[m][n][r] * 0.125f + sT[dy * 63 + dx];
          sv[n] = val;
          mx = fmaxf(mx, val);
        }
        mx = fmaxf(mx, __shfl_xor(mx, 1));
        mx = fmaxf(mx, __shfl_xor(mx, 2));
        mx = fmaxf(mx, __shfl_xor(mx, 4));
        mx = fmaxf(mx, __shfl_xor(mx, 8));
        const float mold = mrow[m][r];
        const float mnew = fmaxf(mold, mx);
        const float alpha = __expf(mold - mnew);
        float rs = 0.f;
        const int prow = (w * 32 + m * 16 + ((lane >> 4) << 2) + r) * 72;
#pragma unroll
        for (int n = 0; n < 4; ++n) {
          const float p = __expf(sv[n] - mnew);
          rs += p;
          sP[prow + n * 16 + (lane & 15)] = f2bf(p);
        }
        rs += __shfl_xor(rs, 1);
        rs += __shfl_xor(rs, 2);
        rs += __shfl_xor(rs, 4);
        rs += __shfl_xor(rs, 8);
        lrow[m][r] = lrow[m][r] * alpha + rs;
        mrow[m][r] = mnew;
#pragma unroll
        for (int n = 0; n < 4; ++n) accO[m][n][r] *= alpha;
      }
    }
    __syncthreads();  // P writes visible (and wave-local lgkm drained)

#pragma unroll
    for (int ks = 0; ks < 2; ++ks) {
      s16x8 pf[2], vf[4];
#pragma unroll
      for (int m = 0; m < 2; ++m)
        pf[m] = *(const s16x8*)(sP + (w * 32 + m * 16 + (lane & 15)) * 72 + ks * 32 + (lane >> 4) * 8);
#pragma unroll
      for (int n = 0; n < 4; ++n)
        vf[n] = *(const s16x8*)(sV + (n * 16 + (lane & 15)) * 72 + ks * 32 + (lane >> 4) * 8);
#pragma unroll
      for (int m = 0; m < 2; ++m)
#pragma unroll
        for (int n = 0; n < 4; ++n)
          accO[m][n] = MFMA16(pf[m], vf[n], accO[m][n]);
    }
  }

#pragma unroll
  for (int m = 0; m < 2; ++m)
#pragma unroll
    for (int n = 0; n < 4; ++n)
#pragma unroll
      for (int r = 0; r < 4; ++r) {
        const int qi = q0 + w * 32 + m * 16 + ((lane >> 4) << 2) + r;
        const int d = n * 16 + (lane & 15);
        const float o = accO[m][n][r] / lrow[m][r];
        ctx[((size_t)(b * 1024 + qi)) * 1024 + h * 64 + d] = f2bf(o);
      }
}

// ---------------- launch ----------------
extern "C" void kernel_launch(void* const* d_in, const int* in_sizes, int n_in,
                              void* d_out, int out_size, void* d_ws, size_t ws_size,
                              hipStream_t stream) {
  const float* query = (const float*)d_in[0];
  const float* key   = (const float*)d_in[1];
  const float* value = (const float*)d_in[2];
  const float* wq = (const float*)d_in[3];
  const float* bq = (const float*)d_in[4];
  const float* wk = (const float*)d_in[5];
  const float* bk = (const float*)d_in[6];
  const float* wv = (const float*)d_in[7];
  const float* bv = (const float*)d_in[8];
  const float* wo = (const float*)d_in[9];
  const float* bo = (const float*)d_in[10];
  const float* pw0 = (const float*)d_in[11];
  const float* pb0 = (const float*)d_in[12];
  const float* pw1 = (const float*)d_in[13];
  const float* pb1 = (const float*)d_in[14];
  const float* pw2 = (const float*)d_in[15];
  const float* pb2 = (const float*)d_in[16];
  // patch_height/patch_width fixed at 32 by the problem (S = 1024 = 32*32)

  char* ws = (char*)d_ws;
  u16* Xq  = (u16*)(ws + 0);
  u16* Xk  = (u16*)(ws + 8388608);
  u16* Xv  = (u16*)(ws + 16777216);
  u16* Wtq = (u16*)(ws + 25165824);
  u16* Wtk = (u16*)(ws + 27262976);
  u16* Wtv = (u16*)(ws + 29360128);
  u16* Wto = (u16*)(ws + 31457280);
  u16* Qb  = (u16*)(ws + 33554432);
  u16* Kb  = (u16*)(ws + 41943040);
  u16* Vb  = (u16*)(ws + 50331648);
  u16* Vtb = (u16*)(ws + 58720256);
  u16* ctx = (u16*)(ws + 67108864);
  float* tbl = (float*)(ws + 75497472);

  k_cast<<<dim3(4096, 1, 3), 256, 0, stream>>>(query, key, value, Xq, Xk, Xv);
  k_transpose_w<<<dim3(16, 16, 4), 256, 0, stream>>>(wq, wk, wv, wo, Wtq, Wtk, Wtv, Wto);
  k_posbias<<<dim3(249), 256, 0, stream>>>(pw0, pb0, pw1, pb1, pw2, pb2, tbl);
  k_gemm<0><<<dim3(8, 32, 3), 256, 0, stream>>>(Xq, Xk, Xv, Wtq, Wtk, Wtv,
                                                bq, bk, bv, Qb, Kb, Vb, 4096, 1024, 1024);
  k_vt<<<dim3(16, 64), 256, 0, stream>>>(Vb, Vtb);
  k_attn<<<dim3(8, 64), 256, 0, stream>>>(Qb, Kb, Vtb, tbl, ctx);
  k_gemm<1><<<dim3(8, 32, 1), 256, 0, stream>>>(ctx, ctx, ctx, Wto, Wto, Wto,
                                                bo, bo, bo, d_out, d_out, d_out, 4096, 1024, 1024);
}

// Round 2
// 216.161 us; speedup vs baseline: 1.0116x; 1.0116x over previous
//
#include <hip/hip_runtime.h>
#include <stdint.h>

typedef unsigned short u16;
typedef unsigned int   u32;
typedef __attribute__((ext_vector_type(4))) float f32x4;
typedef __attribute__((ext_vector_type(8))) short s16x8;

__device__ __forceinline__ u16 f2bf(float f) {
  u32 u = __builtin_bit_cast(u32, f);
  u = (u + 0x7FFFu + ((u >> 16) & 1u)) >> 16;
  return (u16)u;
}

__device__ __forceinline__ u32 cvt_pk_bf16(float lo, float hi) {
  u32 r;
  asm("v_cvt_pk_bf16_f32 %0, %1, %2" : "=v"(r) : "v"(lo), "v"(hi));
  return r;
}

__device__ __forceinline__ void gload_lds16(const void* g, void* l) {
  __builtin_amdgcn_global_load_lds((const __attribute__((address_space(1))) void*)g,
                                   (__attribute__((address_space(3))) void*)l,
                                   16, 0, 0);
}

#define MFMA16(a, b, c) __builtin_amdgcn_mfma_f32_16x16x32_bf16((a), (b), (c), 0, 0, 0)

// ---------------- cast fp32 -> bf16 (query/key/value) ----------------
__global__ void k_cast(const float* __restrict__ q, const float* __restrict__ k,
                       const float* __restrict__ v,
                       u16* __restrict__ oq, u16* __restrict__ ok, u16* __restrict__ ov) {
  const int z = blockIdx.z;
  const float* src = (z == 0) ? q : (z == 1) ? k : v;
  u16* dst = (z == 0) ? oq : (z == 1) ? ok : ov;
  const int i = (blockIdx.x * 256 + threadIdx.x) * 4;
  const float4 f = *(const float4*)(src + i);
  ushort4 o4;
  o4.x = f2bf(f.x); o4.y = f2bf(f.y); o4.z = f2bf(f.z); o4.w = f2bf(f.w);
  *(ushort4*)(dst + i) = o4;
}

// ---------------- transpose+cast weights: W[K][N] fp32 -> Wt[N][K] bf16 ----------------
__global__ void k_transpose_w(const float* __restrict__ w0, const float* __restrict__ w1,
                              const float* __restrict__ w2, const float* __restrict__ w3,
                              u16* __restrict__ o0, u16* __restrict__ o1,
                              u16* __restrict__ o2, u16* __restrict__ o3) {
  __shared__ float t[64][65];
  const int z = blockIdx.z;
  const float* w = (z == 0) ? w0 : (z == 1) ? w1 : (z == 2) ? w2 : w3;
  u16* o = (z == 0) ? o0 : (z == 1) ? o1 : (z == 2) ? o2 : o3;
  const int k0 = blockIdx.x * 64;
  const int n0 = blockIdx.y * 64;
  const int tx = threadIdx.x & 63, ty = threadIdx.x >> 6;
#pragma unroll
  for (int i = 0; i < 16; ++i) {
    const int r = ty * 16 + i;
    t[r][tx] = w[(size_t)(k0 + r) * 1024 + n0 + tx];
  }
  __syncthreads();
#pragma unroll
  for (int i = 0; i < 16; ++i) {
    const int r = ty * 16 + i;
    o[(size_t)(n0 + r) * 1024 + k0 + tx] = f2bf(t[tx][r]);
  }
}

// ---------------- position-bias MLP on the 63x63 unique rel offsets ----------------
// tbl layout: [16 heads][3969]  (entry p = (dy+31)*63 + (dx+31))
__global__ void k_posbias(const float* __restrict__ w0, const float* __restrict__ b0,
                          const float* __restrict__ w1, const float* __restrict__ b1,
                          const float* __restrict__ w2, const float* __restrict__ b2,
                          float* __restrict__ tbl) {
  __shared__ float h0[16][256];
  __shared__ float h1[16][256];
  const int t = threadIdx.x;
  const int p0 = blockIdx.x * 16;
  {
    const float wy = w0[t], wx = w0[256 + t], bb = b0[t];
#pragma unroll
    for (int r = 0; r < 16; ++r) {
      int p = p0 + r; if (p > 3968) p = 3968;
      const float dy = (float)(p / 63 - 31);
      const float dx = (float)(p % 63 - 31);
      const float v = dy * wy + dx * wx + bb;
      h0[r][t] = v > 0.f ? v : 0.01f * v;
    }
  }
  __syncthreads();
  {
    float acc[16];
    const float bb = b1[t];
#pragma unroll
    for (int r = 0; r < 16; ++r) acc[r] = bb;
    for (int k = 0; k < 256; ++k) {
      const float w = w1[k * 256 + t];
#pragma unroll
      for (int r = 0; r < 16; ++r) acc[r] += h0[r][k] * w;
    }
#pragma unroll
    for (int r = 0; r < 16; ++r) {
      const float v = acc[r];
      h1[r][t] = v > 0.f ? v : 0.01f * v;
    }
  }
  __syncthreads();
  {
    const int r = t >> 4, hh = t & 15;
    float acc = b2[hh];
    for (int k = 0; k < 256; ++k) acc += h1[r][k] * w2[k * 16 + hh];
    const int p = p0 + r;
    if (p < 3969) tbl[hh * 3969 + p] = acc;
  }
}

// ---------------- bf16 GEMM, 128x128 tile, BK=64, m97 structure ----------------
template <int MODE>
__global__ __launch_bounds__(256) void k_gemm(
    const u16* __restrict__ A0, const u16* __restrict__ A1, const u16* __restrict__ A2,
    const u16* __restrict__ B0, const u16* __restrict__ B1, const u16* __restrict__ B2,
    const float* __restrict__ c0, const float* __restrict__ c1, const float* __restrict__ c2,
    void* __restrict__ o0, void* __restrict__ o1, void* __restrict__ o2,
    int Mdim, int Ndim, int Kdim) {
  __shared__ u16 sA[128 * 64];
  __shared__ u16 sB[128 * 64];
  const int z = blockIdx.z;
  const u16* A  = (z == 0) ? A0 : (z == 1) ? A1 : A2;
  const u16* Bt = (z == 0) ? B0 : (z == 1) ? B1 : B2;
  const float* bias = (z == 0) ? c0 : (z == 1) ? c1 : c2;

  const int tid = threadIdx.x, lane = tid & 63, w = tid >> 6;
  const int wr = w >> 1, wc = w & 1;
  const int m0 = blockIdx.y * 128, n0 = blockIdx.x * 128;

  f32x4 acc[4][4] = {};

  const u16* aRow = A  + (size_t)(m0 + w * 32 + (lane >> 3)) * Kdim + (lane & 7) * 8;
  const u16* bRow = Bt + (size_t)(n0 + w * 32 + (lane >> 3)) * Kdim + (lane & 7) * 8;

  for (int kt = 0; kt < Kdim; kt += 64) {
    __syncthreads();
#pragma unroll
    for (int i = 0; i < 4; ++i)
      gload_lds16(aRow + (size_t)i * 8 * Kdim + kt, sA + (w * 32 + i * 8) * 64);
#pragma unroll
    for (int i = 0; i < 4; ++i)
      gload_lds16(bRow + (size_t)i * 8 * Kdim + kt, sB + (w * 32 + i * 8) * 64);
    __syncthreads();
#pragma unroll
    for (int ks = 0; ks < 2; ++ks) {
      s16x8 af[4], bf[4];
#pragma unroll
      for (int m = 0; m < 4; ++m)
        af[m] = *(const s16x8*)(sA + (wr * 64 + m * 16 + (lane & 15)) * 64 + ks * 32 + (lane >> 4) * 8);
#pragma unroll
      for (int n = 0; n < 4; ++n)
        bf[n] = *(const s16x8*)(sB + (wc * 64 + n * 16 + (lane & 15)) * 64 + ks * 32 + (lane >> 4) * 8);
#pragma unroll
      for (int m = 0; m < 4; ++m)
#pragma unroll
        for (int n = 0; n < 4; ++n)
          acc[m][n] = MFMA16(af[m], bf[n], acc[m][n]);
    }
  }

  if (MODE == 0) {
    u16* out = (u16*)((z == 0) ? o0 : (z == 1) ? o1 : o2);
#pragma unroll
    for (int m = 0; m < 4; ++m) {
      const int gm = m0 + wr * 64 + m * 16 + ((lane >> 4) << 2);
#pragma unroll
      for (int n = 0; n < 4; ++n) {
        const int gn = n0 + wc * 64 + n * 16 + (lane & 15);
        const float bv = bias[gn];
        const int hh = gn >> 6, dd = gn & 63;
#pragma unroll
        for (int r = 0; r < 4; ++r) {
          const int row = gm + r;
          const int batch = row >> 10, ss = row & 1023;
          out[(((size_t)(batch * 16 + hh)) * 1024 + ss) * 64 + dd] = f2bf(acc[m][n][r] + bv);
        }
      }
    }
  } else {
    float* out = (float*)o0;
#pragma unroll
    for (int m = 0; m < 4; ++m) {
      const int gm = m0 + wr * 64 + m * 16 + ((lane >> 4) << 2);
#pragma unroll
      for (int n = 0; n < 4; ++n) {
        const int gn = n0 + wc * 64 + n * 16 + (lane & 15);
        const float bv = bias[gn];
#pragma unroll
        for (int r = 0; r < 4; ++r)
          out[(size_t)(gm + r) * Ndim + gn] = acc[m][n][r] + bv;
      }
    }
  }
}

// ---------------- V [bh][s][d] -> Vt [bh][d][s] (bf16 tiled transpose) ----------------
__global__ void k_vt(const u16* __restrict__ Vb, u16* __restrict__ Vt) {
  __shared__ u32 t[64][65];
  const int bh = blockIdx.y, s0 = blockIdx.x * 64;
  const int tx = threadIdx.x & 63, ty = threadIdx.x >> 6;
  const u16* src = Vb + (size_t)bh * 65536;
  u16* dst = Vt + (size_t)bh * 65536;
#pragma unroll
  for (int i = 0; i < 16; ++i) {
    const int r = ty * 16 + i;
    t[r][tx] = src[(size_t)(s0 + r) * 64 + tx];
  }
  __syncthreads();
#pragma unroll
  for (int i = 0; i < 16; ++i) {
    const int r = ty * 16 + i;  // d index
    dst[(size_t)r * 1024 + s0 + tx] = (u16)t[tx][r];
  }
}

// ---------------- flash attention, swapped-operand in-register softmax ----------------
// Per WG: 4 waves x 32 q-rows = 128 q. KV tile 64. d_k = 64.
// QK^T swapped: sc = mfma(K, Q) -> lane holds 16 scores (kv) for ONE q (= lane&15).
// PV swapped:   accO = mfma(Vt, P) -> col = q matches softmax layout; state stays lane-local.
__global__ __launch_bounds__(256, 4) void k_attn(
    const u16* __restrict__ Qb,   // [64 bh][1024][64]
    const u16* __restrict__ Kb,   // [64 bh][1024][64]
    const u16* __restrict__ Vt,   // [64 bh][64][1024]
    const float* __restrict__ tbl,// [16][3969]
    u16* __restrict__ ctx) {      // [4096][1024]
  __shared__ u16 sK[64 * 64];     // [kv][d], XOR-swizzled 16B slots
  __shared__ u16 sV[64 * 64];     // [d][kv], XOR-swizzled 16B slots
  __shared__ u32 sP[4][16][32];   // per-wave P bounce buffer, XOR-swizzled dwords
  __shared__ float sT[3969];
  const int tid = threadIdx.x, lane = tid & 63, w = tid >> 6;
  const int qlo = lane & 15, g = lane >> 4;
  const int bh = blockIdx.y, h = bh & 15, b = bh >> 4;
  const int q0 = blockIdx.x * 128;
  const u16* Qp = Qb + (size_t)bh * (1024 * 64);
  const u16* Kp = Kb + (size_t)bh * (1024 * 64);
  const u16* Vp = Vt + (size_t)bh * (64 * 1024);

  for (int i = tid; i < 3969; i += 256) sT[i] = tbl[h * 3969 + i];

  // Q fragments (B-operand layout: lane holds Q[q = qlo][d = ks*32 + g*8 .. +8])
  s16x8 qf[2][2];
  int yq[2], xq[2];
#pragma unroll
  for (int m = 0; m < 2; ++m) {
    const int qi = q0 + w * 32 + m * 16 + qlo;
    yq[m] = qi >> 5; xq[m] = qi & 31;
#pragma unroll
    for (int ks = 0; ks < 2; ++ks)
      qf[m][ks] = *(const s16x8*)(Qp + (size_t)qi * 64 + ks * 32 + g * 8);
  }

  f32x4 accO[2][4] = {};
  float mrow[2] = {-3e38f, -3e38f}, lrow[2] = {0.f, 0.f};

  // staging geometry: per wave-round 8 rows x 8 slots of 16B; swizzle source col
  const int srow = lane >> 3;            // 0..7 = row within round = row&7
  const int sslot = lane & 7;
  const int scol = ((sslot ^ srow) * 8); // u16 units
  const int swz = (qlo & 7) << 3;        // u16-index XOR for fragment reads
  u16* const myP = (u16*)&sP[w][0][0];

  for (int kv0 = 0; kv0 < 1024; kv0 += 64) {
    __syncthreads();
#pragma unroll
    for (int i = 0; i < 2; ++i) {
      const int row = w * 16 + i * 8 + srow;
      gload_lds16(Kp + (size_t)(kv0 + row) * 64 + scol, sK + row * 64 + sslot * 8);
      gload_lds16(Vp + (size_t)row * 1024 + kv0 + scol, sV + row * 64 + sslot * 8);
    }
    __syncthreads();

    // QK^T (swapped): sc[m][n], lane holds kv = n*16 + g*4 + reg for q = qlo
    f32x4 sc[2][4] = {};
#pragma unroll
    for (int ks = 0; ks < 2; ++ks) {
      s16x8 kf[4];
#pragma unroll
      for (int n = 0; n < 4; ++n)
        kf[n] = *(const s16x8*)(sK + (n * 16 + qlo) * 64 + ((ks * 32 + g * 8) ^ swz));
#pragma unroll
      for (int m = 0; m < 2; ++m)
#pragma unroll
        for (int n = 0; n < 4; ++n)
          sc[m][n] = MFMA16(kf[n], qf[m][ks], sc[m][n]);
    }

#pragma unroll
    for (int m = 0; m < 2; ++m) {
      // scores + bias, in-lane max over 16
      float p[16];
      float mx = -3e38f;
#pragma unroll
      for (int n = 0; n < 4; ++n)
#pragma unroll
        for (int r = 0; r < 4; ++r) {
          const int kvi = kv0 + n * 16 + g * 4 + r;
          const int dy = yq[m] - (kvi >> 5) + 31;
          const int dx = xq[m] - (kvi & 31) + 31;
          const float val = sc[m][n][r] * 0.125f + sT[dy * 63 + dx];
          p[n * 4 + r] = val;
          mx = fmaxf(mx, val);
        }
      mx = fmaxf(mx, __shfl_xor(mx, 16));
      mx = fmaxf(mx, __shfl_xor(mx, 32));
      const float mnew = fmaxf(mrow[m], mx);
      const float alpha = __expf(mrow[m] - mnew);
      mrow[m] = mnew;
      float rs = 0.f;
#pragma unroll
      for (int i = 0; i < 16; ++i) { p[i] = __expf(p[i] - mnew); rs += p[i]; }
      rs += __shfl_xor(rs, 16);
      rs += __shfl_xor(rs, 32);
      lrow[m] = lrow[m] * alpha + rs;
#pragma unroll
      for (int n = 0; n < 4; ++n) accO[m][n] *= alpha;

      // pack P -> wave-private swizzled LDS (in-order DS pipe, no barrier)
      {
        u32* const prow = &sP[w][qlo][0];
        const int dswz = (qlo & 7) << 2;
#pragma unroll
        for (int n = 0; n < 4; ++n)
#pragma unroll
          for (int r2 = 0; r2 < 2; ++r2)
            prow[(n * 8 + g * 2 + r2) ^ dswz] =
                cvt_pk_bf16(p[n * 4 + 2 * r2], p[n * 4 + 2 * r2 + 1]);
      }

      // PV (swapped): accO[m][n] += mfma(Vt_frag, P_frag)
#pragma unroll
      for (int ks = 0; ks < 2; ++ks) {
        const s16x8 pf = *(const s16x8*)(myP + qlo * 64 + ((ks * 32 + g * 8) ^ swz));
        s16x8 av[4];
#pragma unroll
        for (int n = 0; n < 4; ++n)
          av[n] = *(const s16x8*)(sV + (n * 16 + qlo) * 64 + ((ks * 32 + g * 8) ^ swz));
#pragma unroll
        for (int n = 0; n < 4; ++n)
          accO[m][n] = MFMA16(av[n], pf, accO[m][n]);
      }
    }
  }

  // epilogue: lane holds, per m: q = qlo, d = n*16 + g*4 + reg
#pragma unroll
  for (int m = 0; m < 2; ++m) {
    const int qi = q0 + w * 32 + m * 16 + qlo;
    const float inv = 1.0f / lrow[m];
#pragma unroll
    for (int n = 0; n < 4; ++n) {
      ushort4 o4;
      o4.x = f2bf(accO[m][n][0] * inv);
      o4.y = f2bf(accO[m][n][1] * inv);
      o4.z = f2bf(accO[m][n][2] * inv);
      o4.w = f2bf(accO[m][n][3] * inv);
      *(ushort4*)(ctx + ((size_t)(b * 1024 + qi)) * 1024 + h * 64 + n * 16 + g * 4) = o4;
    }
  }
}

// ---------------- launch ----------------
extern "C" void kernel_launch(void* const* d_in, const int* in_sizes, int n_in,
                              void* d_out, int out_size, void* d_ws, size_t ws_size,
                              hipStream_t stream) {
  const float* query = (const float*)d_in[0];
  const float* key   = (const float*)d_in[1];
  const float* value = (const float*)d_in[2];
  const float* wq = (const float*)d_in[3];
  const float* bq = (const float*)d_in[4];
  const float* wk = (const float*)d_in[5];
  const float* bk = (const float*)d_in[6];
  const float* wv = (const float*)d_in[7];
  const float* bv = (const float*)d_in[8];
  const float* wo = (const float*)d_in[9];
  const float* bo = (const float*)d_in[10];
  const float* pw0 = (const float*)d_in[11];
  const float* pb0 = (const float*)d_in[12];
  const float* pw1 = (const float*)d_in[13];
  const float* pb1 = (const float*)d_in[14];
  const float* pw2 = (const float*)d_in[15];
  const float* pb2 = (const float*)d_in[16];

  char* ws = (char*)d_ws;
  u16* Xq  = (u16*)(ws + 0);
  u16* Xk  = (u16*)(ws + 8388608);
  u16* Xv  = (u16*)(ws + 16777216);
  u16* Wtq = (u16*)(ws + 25165824);
  u16* Wtk = (u16*)(ws + 27262976);
  u16* Wtv = (u16*)(ws + 29360128);
  u16* Wto = (u16*)(ws + 31457280);
  u16* Qb  = (u16*)(ws + 33554432);
  u16* Kb  = (u16*)(ws + 41943040);
  u16* Vb  = (u16*)(ws + 50331648);
  u16* Vtb = (u16*)(ws + 58720256);
  u16* ctx = (u16*)(ws + 67108864);
  float* tbl = (float*)(ws + 75497472);

  k_cast<<<dim3(4096, 1, 3), 256, 0, stream>>>(query, key, value, Xq, Xk, Xv);
  k_transpose_w<<<dim3(16, 16, 4), 256, 0, stream>>>(wq, wk, wv, wo, Wtq, Wtk, Wtv, Wto);
  k_posbias<<<dim3(249), 256, 0, stream>>>(pw0, pb0, pw1, pb1, pw2, pb2, tbl);
  k_gemm<0><<<dim3(8, 32, 3), 256, 0, stream>>>(Xq, Xk, Xv, Wtq, Wtk, Wtv,
                                                bq, bk, bv, Qb, Kb, Vb, 4096, 1024, 1024);
  k_vt<<<dim3(16, 64), 256, 0, stream>>>(Vb, Vtb);
  k_attn<<<dim3(8, 64), 256, 0, stream>>>(Qb, Kb, Vtb, tbl, ctx);
  k_gemm<1><<<dim3(8, 32, 1), 256, 0, stream>>>(ctx, ctx, ctx, Wto, Wto, Wto,
                                                bo, bo, bo, d_out, d_out, d_out, 4096, 1024, 1024);
}

// Round 6
// 170.347 us; speedup vs baseline: 1.2836x; 1.2689x over previous
//
#include <hip/hip_runtime.h>
#include <stdint.h>

typedef unsigned short u16;
typedef unsigned int   u32;
typedef __attribute__((ext_vector_type(4))) float f32x4;
typedef __attribute__((ext_vector_type(8))) short s16x8;
typedef __attribute__((ext_vector_type(2))) u32 u32x2;

__device__ __forceinline__ u16 f2bf(float f) {
  u32 u = __builtin_bit_cast(u32, f);
  u = (u + 0x7FFFu + ((u >> 16) & 1u)) >> 16;
  return (u16)u;
}

__device__ __forceinline__ u32 cvt_pk_bf16(float lo, float hi) {
  u32 r;
  asm("v_cvt_pk_bf16_f32 %0, %1, %2" : "=v"(r) : "v"(lo), "v"(hi));
  return r;
}

__device__ __forceinline__ void gload_lds16(const void* g, void* l) {
  __builtin_amdgcn_global_load_lds((const __attribute__((address_space(1))) void*)g,
                                   (__attribute__((address_space(3))) void*)l,
                                   16, 0, 0);
}

#define MFMA16(a, b, c) __builtin_amdgcn_mfma_f32_16x16x32_bf16((a), (b), (c), 0, 0, 0)

// ---------------- cast fp32 -> bf16 (query/key/value) ----------------
__global__ void k_cast(const float* __restrict__ q, const float* __restrict__ k,
                       const float* __restrict__ v,
                       u16* __restrict__ oq, u16* __restrict__ ok, u16* __restrict__ ov) {
  const int z = blockIdx.z;
  const float* src = (z == 0) ? q : (z == 1) ? k : v;
  u16* dst = (z == 0) ? oq : (z == 1) ? ok : ov;
  const int i = (blockIdx.x * 256 + threadIdx.x) * 4;
  const float4 f = *(const float4*)(src + i);
  ushort4 o4;
  o4.x = f2bf(f.x); o4.y = f2bf(f.y); o4.z = f2bf(f.z); o4.w = f2bf(f.w);
  *(ushort4*)(dst + i) = o4;
}

// ---------------- transpose+cast weights: W[K][N] fp32 -> Wt[N][K] bf16 ----------------
__global__ void k_transpose_w(const float* __restrict__ w0, const float* __restrict__ w1,
                              const float* __restrict__ w2, const float* __restrict__ w3,
                              u16* __restrict__ o0, u16* __restrict__ o1,
                              u16* __restrict__ o2, u16* __restrict__ o3) {
  __shared__ float t[64][65];
  const int z = blockIdx.z;
  const float* w = (z == 0) ? w0 : (z == 1) ? w1 : (z == 2) ? w2 : w3;
  u16* o = (z == 0) ? o0 : (z == 1) ? o1 : (z == 2) ? o2 : o3;
  const int k0 = blockIdx.x * 64;
  const int n0 = blockIdx.y * 64;
  const int tx = threadIdx.x & 63, ty = threadIdx.x >> 6;
#pragma unroll
  for (int i = 0; i < 16; ++i) {
    const int r = ty * 16 + i;
    t[r][tx] = w[(size_t)(k0 + r) * 1024 + n0 + tx];
  }
  __syncthreads();
#pragma unroll
  for (int i = 0; i < 16; ++i) {
    const int r = ty * 16 + i;
    o[(size_t)(n0 + r) * 1024 + k0 + tx] = f2bf(t[tx][r]);
  }
}

// ---------------- position-bias MLP on the 63x63 unique rel offsets ----------------
// tbl layout: [16 heads][3969]  (entry p = (dy+31)*63 + (dx+31)); natural-log domain.
__global__ void k_posbias(const float* __restrict__ w0, const float* __restrict__ b0,
                          const float* __restrict__ w1, const float* __restrict__ b1,
                          const float* __restrict__ w2, const float* __restrict__ b2,
                          float* __restrict__ tbl) {
  __shared__ float h0[16][256];
  __shared__ float h1[16][256];
  const int t = threadIdx.x;
  const int p0 = blockIdx.x * 16;
  {
    const float wy = w0[t], wx = w0[256 + t], bb = b0[t];
#pragma unroll
    for (int r = 0; r < 16; ++r) {
      int p = p0 + r; if (p > 3968) p = 3968;
      const float dy = (float)(p / 63 - 31);
      const float dx = (float)(p % 63 - 31);
      const float v = dy * wy + dx * wx + bb;
      h0[r][t] = v > 0.f ? v : 0.01f * v;
    }
  }
  __syncthreads();
  {
    float acc[16];
    const float bb = b1[t];
#pragma unroll
    for (int r = 0; r < 16; ++r) acc[r] = bb;
    for (int k = 0; k < 256; ++k) {
      const float w = w1[k * 256 + t];
#pragma unroll
      for (int r = 0; r < 16; ++r) acc[r] += h0[r][k] * w;
    }
#pragma unroll
    for (int r = 0; r < 16; ++r) {
      const float v = acc[r];
      h1[r][t] = v > 0.f ? v : 0.01f * v;
    }
  }
  __syncthreads();
  {
    const int r = t >> 4, hh = t & 15;
    float acc = b2[hh];
    for (int k = 0; k < 256; ++k) acc += h1[r][k] * w2[k * 16 + hh];
    const int p = p0 + r;
    if (p < 3969) tbl[hh * 3969 + p] = acc;
  }
}

// ---------------- bf16 GEMM, 128x128 tile, BK=64, m97 structure ----------------
template <int MODE>
__global__ __launch_bounds__(256) void k_gemm(
    const u16* __restrict__ A0, const u16* __restrict__ A1, const u16* __restrict__ A2,
    const u16* __restrict__ B0, const u16* __restrict__ B1, const u16* __restrict__ B2,
    const float* __restrict__ c0, const float* __restrict__ c1, const float* __restrict__ c2,
    void* __restrict__ o0, void* __restrict__ o1, void* __restrict__ o2,
    int Mdim, int Ndim, int Kdim) {
  __shared__ u16 sA[128 * 64];
  __shared__ u16 sB[128 * 64];
  const int z = blockIdx.z;
  const u16* A  = (z == 0) ? A0 : (z == 1) ? A1 : A2;
  const u16* Bt = (z == 0) ? B0 : (z == 1) ? B1 : B2;
  const float* bias = (z == 0) ? c0 : (z == 1) ? c1 : c2;

  const int tid = threadIdx.x, lane = tid & 63, w = tid >> 6;
  const int wr = w >> 1, wc = w & 1;
  const int m0 = blockIdx.y * 128, n0 = blockIdx.x * 128;

  f32x4 acc[4][4] = {};

  const u16* aRow = A  + (size_t)(m0 + w * 32 + (lane >> 3)) * Kdim + (lane & 7) * 8;
  const u16* bRow = Bt + (size_t)(n0 + w * 32 + (lane >> 3)) * Kdim + (lane & 7) * 8;

  for (int kt = 0; kt < Kdim; kt += 64) {
    __syncthreads();
#pragma unroll
    for (int i = 0; i < 4; ++i)
      gload_lds16(aRow + (size_t)i * 8 * Kdim + kt, sA + (w * 32 + i * 8) * 64);
#pragma unroll
    for (int i = 0; i < 4; ++i)
      gload_lds16(bRow + (size_t)i * 8 * Kdim + kt, sB + (w * 32 + i * 8) * 64);
    __syncthreads();
#pragma unroll
    for (int ks = 0; ks < 2; ++ks) {
      s16x8 af[4], bf[4];
#pragma unroll
      for (int m = 0; m < 4; ++m)
        af[m] = *(const s16x8*)(sA + (wr * 64 + m * 16 + (lane & 15)) * 64 + ks * 32 + (lane >> 4) * 8);
#pragma unroll
      for (int n = 0; n < 4; ++n)
        bf[n] = *(const s16x8*)(sB + (wc * 64 + n * 16 + (lane & 15)) * 64 + ks * 32 + (lane >> 4) * 8);
#pragma unroll
      for (int m = 0; m < 4; ++m)
#pragma unroll
        for (int n = 0; n < 4; ++n)
          acc[m][n] = MFMA16(af[m], bf[n], acc[m][n]);
    }
  }

  if (MODE == 0) {
    u16* out = (u16*)((z == 0) ? o0 : (z == 1) ? o1 : o2);
#pragma unroll
    for (int m = 0; m < 4; ++m) {
      const int gm = m0 + wr * 64 + m * 16 + ((lane >> 4) << 2);
#pragma unroll
      for (int n = 0; n < 4; ++n) {
        const int gn = n0 + wc * 64 + n * 16 + (lane & 15);
        const float bv = bias[gn];
        const int hh = gn >> 6, dd = gn & 63;
#pragma unroll
        for (int r = 0; r < 4; ++r) {
          const int row = gm + r;
          const int batch = row >> 10, ss = row & 1023;
          out[(((size_t)(batch * 16 + hh)) * 1024 + ss) * 64 + dd] = f2bf(acc[m][n][r] + bv);
        }
      }
    }
  } else {
    float* out = (float*)o0;
#pragma unroll
    for (int m = 0; m < 4; ++m) {
      const int gm = m0 + wr * 64 + m * 16 + ((lane >> 4) << 2);
#pragma unroll
      for (int n = 0; n < 4; ++n) {
        const int gn = n0 + wc * 64 + n * 16 + (lane & 15);
        const float bv = bias[gn];
#pragma unroll
        for (int r = 0; r < 4; ++r)
          out[(size_t)(gm + r) * Ndim + gn] = acc[m][n][r] + bv;
      }
    }
  }
}

// ---------------- V [bh][s][d] -> Vt [bh][d][s] (bf16 tiled transpose) ----------------
__global__ void k_vt(const u16* __restrict__ Vb, u16* __restrict__ Vt) {
  __shared__ u32 t[64][65];
  const int bh = blockIdx.y, s0 = blockIdx.x * 64;
  const int tx = threadIdx.x & 63, ty = threadIdx.x >> 6;
  const u16* src = Vb + (size_t)bh * 65536;
  u16* dst = Vt + (size_t)bh * 65536;
#pragma unroll
  for (int i = 0; i < 16; ++i) {
    const int r = ty * 16 + i;
    t[r][tx] = src[(size_t)(s0 + r) * 64 + tx];
  }
  __syncthreads();
#pragma unroll
  for (int i = 0; i < 16; ++i) {
    const int r = ty * 16 + i;  // d index
    dst[(size_t)r * 1024 + s0 + tx] = (u16)t[tx][r];
  }
}

// ---------------- flash attention v6: R2 softmax + R3 structure + per-m sP ------------
// Per WG: 4 waves x 32 q-rows = 128 q. KV tile 64, double-buffered.
// BUGFIX vs R3-R5: sP is indexed by m (sP[w][m][qlo][...]). The hoisted-PV restructure
// in R3 overwrote m=0's P with m=1's before PV consumed it (capacity bug, not indexing).
__global__ __launch_bounds__(256, 2) void k_attn(
    const u16* __restrict__ Qb,   // [64 bh][1024][64]
    const u16* __restrict__ Kb,   // [64 bh][1024][64]
    const u16* __restrict__ Vt,   // [64 bh][64][1024]
    const float* __restrict__ tbl,// [16][3969] natural-log-domain bias
    u16* __restrict__ ctx) {      // [4096][1024]
  __shared__ u16 sK[2][64 * 64];    // [kv][d], XOR-swizzled 16B slots
  __shared__ u16 sV[2][64 * 64];    // [d][kv], XOR-swizzled 16B slots
  __shared__ u32 sP[4][2][16][32];  // per-wave, PER-M P bounce, XOR-swizzled dwords
  __shared__ float sTw[2205];       // 35x63 dy-window of the bias table

  // XCD-aware swizzle: all 8 q-blocks of one bh land on one XCD (512 % 8 == 0)
  const int f = blockIdx.x;
  const int nid = (f & 7) * 64 + (f >> 3);
  const int bh = nid >> 3, qblk = nid & 7;
  const int h = bh & 15, b = bh >> 4;
  const int q0 = qblk * 128, yq0 = qblk * 4;

  const int tid = threadIdx.x, lane = tid & 63, w = tid >> 6;
  const int qlo = lane & 15, g = lane >> 4;
  const u16* Qp = Qb + (size_t)bh * (1024 * 64);
  const u16* Kp = Kb + (size_t)bh * (1024 * 64);
  const u16* Vp = Vt + (size_t)bh * (64 * 1024);

  // staging geometry (dst must equal base + lane*16B for global_load_lds)
  const int srow = lane >> 3, sslot = lane & 7;
  const int scol = ((sslot ^ srow) * 8);
  const int swz = (qlo & 7) << 3;

#define STAGE(buf, kv0_)                                                          \
  {                                                                               \
    _Pragma("unroll")                                                             \
    for (int i_ = 0; i_ < 2; ++i_) {                                              \
      const int row_ = w * 16 + i_ * 8 + srow;                                    \
      gload_lds16(Kp + (size_t)((kv0_) + row_) * 64 + scol,                       \
                  &sK[buf][row_ * 64 + sslot * 8]);                               \
      gload_lds16(Vp + (size_t)row_ * 1024 + (kv0_) + scol,                       \
                  &sV[buf][row_ * 64 + sslot * 8]);                               \
    }                                                                             \
  }

  STAGE(0, 0);

  // bias window: rows [yq0, yq0+34] of the 63-wide table -> contiguous 2205 floats
  {
    const float* tblh = tbl + h * 3969 + yq0 * 63;
    for (int i = tid; i < 2205; i += 256) sTw[i] = tblh[i];
  }

  // Q fragments (B-operand: lane holds Q[q=qlo][d = ks*32 + g*8 ..+8])
  s16x8 qf[2][2];
  int W2i[2];
#pragma unroll
  for (int m = 0; m < 2; ++m) {
    const int qi = q0 + w * 32 + m * 16 + qlo;
#pragma unroll
    for (int ks = 0; ks < 2; ++ks)
      qf[m][ks] = *(const s16x8*)(Qp + (size_t)qi * 64 + ks * 32 + g * 8);
    W2i[m] = (w + 31) * 63 + (m * 16 + qlo) + 31 - g * 4;
  }

  f32x4 accO[2][4] = {};
  float mrow[2] = {-3e38f, -3e38f}, lrow[2] = {0.f, 0.f};

  __syncthreads();

  int cur = 0;
  for (int t = 0; t < 16; ++t) {
    const int kv0 = t * 64;
    if (t != 15) STAGE(cur ^ 1, kv0 + 64);

    // QK^T (swapped): lane holds 16 scores (kv = n*16+g*4+r) for q = qlo
    f32x4 sc[2][4] = {};
    __builtin_amdgcn_s_setprio(1);
#pragma unroll
    for (int ks = 0; ks < 2; ++ks) {
      s16x8 kf[4];
#pragma unroll
      for (int n = 0; n < 4; ++n)
        kf[n] = *(const s16x8*)(&sK[cur][(n * 16 + qlo) * 64 + ((ks * 32 + g * 8) ^ swz)]);
#pragma unroll
      for (int m = 0; m < 2; ++m)
#pragma unroll
        for (int n = 0; n < 4; ++n)
          sc[m][n] = MFMA16(kf[n], qf[m][ks], sc[m][n]);
    }
    __builtin_amdgcn_s_setprio(0);

    // R2 online softmax (natural domain, running max, alpha rescale)
    const int bk = (kv0 >> 5) * 63;
#pragma unroll
    for (int m = 0; m < 2; ++m) {
      const int bofs = W2i[m] - bk;
      float sv[16], mx = -3e38f;
#pragma unroll
      for (int n = 0; n < 4; ++n)
#pragma unroll
        for (int r = 0; r < 4; ++r) {
          const float val = sc[m][n][r] * 0.125f +
                            sTw[bofs - ((n >> 1) * 63 + (n & 1) * 16 + r)];
          sv[n * 4 + r] = val;
          mx = fmaxf(mx, val);
        }
      mx = fmaxf(mx, __shfl_xor(mx, 16));
      mx = fmaxf(mx, __shfl_xor(mx, 32));
      const float mold = mrow[m];
      const float mnew = fmaxf(mold, mx);
      const float alpha = __expf(mold - mnew);
      mrow[m] = mnew;
      float p[16], rs = 0.f;
#pragma unroll
      for (int i = 0; i < 16; ++i) { p[i] = __expf(sv[i] - mnew); rs += p[i]; }
      rs += __shfl_xor(rs, 16);
      rs += __shfl_xor(rs, 32);
      lrow[m] = lrow[m] * alpha + rs;
#pragma unroll
      for (int n = 0; n < 4; ++n) accO[m][n] *= alpha;

      // pack P -> wave-private, per-m swizzled LDS (paired b64 writes)
      u32* const prow = &sP[w][m][qlo][0];
      const int dswz = (qlo & 7) << 2;
#pragma unroll
      for (int n = 0; n < 4; ++n) {
        u32x2 pk;
        pk.x = cvt_pk_bf16(p[n * 4 + 0], p[n * 4 + 1]);
        pk.y = cvt_pk_bf16(p[n * 4 + 2], p[n * 4 + 3]);
        *(u32x2*)&prow[(n * 8 + g * 2) ^ dswz] = pk;
      }
    }

    // PV (swapped): accO[m][n] += mfma(V_frag, P_frag); V frags hoisted over m
    __builtin_amdgcn_s_setprio(1);
#pragma unroll
    for (int ks = 0; ks < 2; ++ks) {
      s16x8 av[4];
#pragma unroll
      for (int n = 0; n < 4; ++n)
        av[n] = *(const s16x8*)(&sV[cur][(n * 16 + qlo) * 64 + ((ks * 32 + g * 8) ^ swz)]);
#pragma unroll
      for (int m = 0; m < 2; ++m) {
        const u16* myPm = (const u16*)&sP[w][m][0][0];
        const s16x8 pf = *(const s16x8*)(myPm + qlo * 64 + ((ks * 32 + g * 8) ^ swz));
#pragma unroll
        for (int n = 0; n < 4; ++n)
          accO[m][n] = MFMA16(av[n], pf, accO[m][n]);
      }
    }
    __builtin_amdgcn_s_setprio(0);

    __syncthreads();  // drains prefetch vmcnt + separates buffer epochs
    cur ^= 1;
  }

  // epilogue: lrow already holds the full row sum (reduced in-loop, R2 style)
#pragma unroll
  for (int m = 0; m < 2; ++m) {
    const float inv = 1.0f / lrow[m];
    const int qi = q0 + w * 32 + m * 16 + qlo;
#pragma unroll
    for (int n = 0; n < 4; ++n) {
      ushort4 o4;
      o4.x = f2bf(accO[m][n][0] * inv);
      o4.y = f2bf(accO[m][n][1] * inv);
      o4.z = f2bf(accO[m][n][2] * inv);
      o4.w = f2bf(accO[m][n][3] * inv);
      *(ushort4*)(ctx + ((size_t)(b * 1024 + qi)) * 1024 + h * 64 + n * 16 + g * 4) = o4;
    }
  }
#undef STAGE
}

// ---------------- launch ----------------
extern "C" void kernel_launch(void* const* d_in, const int* in_sizes, int n_in,
                              void* d_out, int out_size, void* d_ws, size_t ws_size,
                              hipStream_t stream) {
  const float* query = (const float*)d_in[0];
  const float* key   = (const float*)d_in[1];
  const float* value = (const float*)d_in[2];
  const float* wq = (const float*)d_in[3];
  const float* bq = (const float*)d_in[4];
  const float* wk = (const float*)d_in[5];
  const float* bk = (const float*)d_in[6];
  const float* wv = (const float*)d_in[7];
  const float* bv = (const float*)d_in[8];
  const float* wo = (const float*)d_in[9];
  const float* bo = (const float*)d_in[10];
  const float* pw0 = (const float*)d_in[11];
  const float* pb0 = (const float*)d_in[12];
  const float* pw1 = (const float*)d_in[13];
  const float* pb1 = (const float*)d_in[14];
  const float* pw2 = (const float*)d_in[15];
  const float* pb2 = (const float*)d_in[16];

  char* ws = (char*)d_ws;
  u16* Xq  = (u16*)(ws + 0);
  u16* Xk  = (u16*)(ws + 8388608);
  u16* Xv  = (u16*)(ws + 16777216);
  u16* Wtq = (u16*)(ws + 25165824);
  u16* Wtk = (u16*)(ws + 27262976);
  u16* Wtv = (u16*)(ws + 29360128);
  u16* Wto = (u16*)(ws + 31457280);
  u16* Qb  = (u16*)(ws + 33554432);
  u16* Kb  = (u16*)(ws + 41943040);
  u16* Vb  = (u16*)(ws + 50331648);
  u16* Vtb = (u16*)(ws + 58720256);
  u16* ctx = (u16*)(ws + 67108864);
  float* tbl = (float*)(ws + 75497472);   // 16*3969*4 = 254016 B

  k_cast<<<dim3(4096, 1, 3), 256, 0, stream>>>(query, key, value, Xq, Xk, Xv);
  k_transpose_w<<<dim3(16, 16, 4), 256, 0, stream>>>(wq, wk, wv, wo, Wtq, Wtk, Wtv, Wto);
  k_posbias<<<dim3(249), 256, 0, stream>>>(pw0, pb0, pw1, pb1, pw2, pb2, tbl);
  k_gemm<0><<<dim3(8, 32, 3), 256, 0, stream>>>(Xq, Xk, Xv, Wtq, Wtk, Wtv,
                                                bq, bk, bv, Qb, Kb, Vb, 4096, 1024, 1024);
  k_vt<<<dim3(16, 64), 256, 0, stream>>>(Vb, Vtb);
  k_attn<<<dim3(512), 256, 0, stream>>>(Qb, Kb, Vtb, tbl, ctx);
  k_gemm<1><<<dim3(8, 32, 1), 256, 0, stream>>>(ctx, ctx, ctx, Wto, Wto, Wto,
                                                bo, bo, bo, d_out, d_out, d_out, 4096, 1024, 1024);
}

// Round 7
// 153.626 us; speedup vs baseline: 1.4234x; 1.1088x over previous
//
#include <hip/hip_runtime.h>
#include <stdint.h>

typedef unsigned short u16;
typedef unsigned int   u32;
typedef __attribute__((ext_vector_type(4))) float f32x4;
typedef __attribute__((ext_vector_type(8))) short s16x8;
typedef __attribute__((ext_vector_type(2))) u32 u32x2;

__device__ __forceinline__ u16 f2bf(float f) {
  u32 u = __builtin_bit_cast(u32, f);
  u = (u + 0x7FFFu + ((u >> 16) & 1u)) >> 16;
  return (u16)u;
}

__device__ __forceinline__ u32 cvt_pk_bf16(float lo, float hi) {
  u32 r;
  asm("v_cvt_pk_bf16_f32 %0, %1, %2" : "=v"(r) : "v"(lo), "v"(hi));
  return r;
}

__device__ __forceinline__ void gload_lds16(const void* g, void* l) {
  __builtin_amdgcn_global_load_lds((const __attribute__((address_space(1))) void*)g,
                                   (__attribute__((address_space(3))) void*)l,
                                   16, 0, 0);
}

#define MFMA16(a, b, c) __builtin_amdgcn_mfma_f32_16x16x32_bf16((a), (b), (c), 0, 0, 0)

// ---------------- cast fp32 -> bf16 (query/key/value) ----------------
__global__ void k_cast(const float* __restrict__ q, const float* __restrict__ k,
                       const float* __restrict__ v,
                       u16* __restrict__ oq, u16* __restrict__ ok, u16* __restrict__ ov) {
  const int z = blockIdx.z;
  const float* src = (z == 0) ? q : (z == 1) ? k : v;
  u16* dst = (z == 0) ? oq : (z == 1) ? ok : ov;
  const int i = (blockIdx.x * 256 + threadIdx.x) * 4;
  const float4 f = *(const float4*)(src + i);
  ushort4 o4;
  o4.x = f2bf(f.x); o4.y = f2bf(f.y); o4.z = f2bf(f.z); o4.w = f2bf(f.w);
  *(ushort4*)(dst + i) = o4;
}

// ---------------- transpose+cast weights: W[K][N] fp32 -> Wt[N][K] bf16 ----------------
__global__ void k_transpose_w(const float* __restrict__ w0, const float* __restrict__ w1,
                              const float* __restrict__ w2, const float* __restrict__ w3,
                              u16* __restrict__ o0, u16* __restrict__ o1,
                              u16* __restrict__ o2, u16* __restrict__ o3) {
  __shared__ float t[64][65];
  const int z = blockIdx.z;
  const float* w = (z == 0) ? w0 : (z == 1) ? w1 : (z == 2) ? w2 : w3;
  u16* o = (z == 0) ? o0 : (z == 1) ? o1 : (z == 2) ? o2 : o3;
  const int k0 = blockIdx.x * 64;
  const int n0 = blockIdx.y * 64;
  const int tx = threadIdx.x & 63, ty = threadIdx.x >> 6;
#pragma unroll
  for (int i = 0; i < 16; ++i) {
    const int r = ty * 16 + i;
    t[r][tx] = w[(size_t)(k0 + r) * 1024 + n0 + tx];
  }
  __syncthreads();
#pragma unroll
  for (int i = 0; i < 16; ++i) {
    const int r = ty * 16 + i;
    o[(size_t)(n0 + r) * 1024 + k0 + tx] = f2bf(t[tx][r]);
  }
}

// ---------------- position-bias MLP on the 63x63 unique rel offsets ----------------
// tbl layout: [16 heads][3969]  (entry p = (dy+31)*63 + (dx+31)); natural-log domain.
__global__ void k_posbias(const float* __restrict__ w0, const float* __restrict__ b0,
                          const float* __restrict__ w1, const float* __restrict__ b1,
                          const float* __restrict__ w2, const float* __restrict__ b2,
                          float* __restrict__ tbl) {
  __shared__ float h0[16][256];
  __shared__ float h1[16][256];
  const int t = threadIdx.x;
  const int p0 = blockIdx.x * 16;
  {
    const float wy = w0[t], wx = w0[256 + t], bb = b0[t];
#pragma unroll
    for (int r = 0; r < 16; ++r) {
      int p = p0 + r; if (p > 3968) p = 3968;
      const float dy = (float)(p / 63 - 31);
      const float dx = (float)(p % 63 - 31);
      const float v = dy * wy + dx * wx + bb;
      h0[r][t] = v > 0.f ? v : 0.01f * v;
    }
  }
  __syncthreads();
  {
    float acc[16];
    const float bb = b1[t];
#pragma unroll
    for (int r = 0; r < 16; ++r) acc[r] = bb;
    for (int k = 0; k < 256; ++k) {
      const float w = w1[k * 256 + t];
#pragma unroll
      for (int r = 0; r < 16; ++r) acc[r] += h0[r][k] * w;
    }
#pragma unroll
    for (int r = 0; r < 16; ++r) {
      const float v = acc[r];
      h1[r][t] = v > 0.f ? v : 0.01f * v;
    }
  }
  __syncthreads();
  {
    const int r = t >> 4, hh = t & 15;
    float acc = b2[hh];
    for (int k = 0; k < 256; ++k) acc += h1[r][k] * w2[k * 16 + hh];
    const int p = p0 + r;
    if (p < 3969) tbl[hh * 3969 + p] = acc;
  }
}

// ---------------- bf16 GEMM v2: 128x128 tile, BK=64, dbuf prefetch + swizzles ---------
// Changes vs R6 (isolated to this kernel):
//  - double-buffered sA/sB; prefetch K-tile t+1 during compute of t; ONE barrier/K-step
//    (the barrier's implicit vmcnt(0) drains loads issued a full compute-phase earlier)
//  - pre-swizzled global source col + XOR-swizzled fragment reads (kills 16-way
//    bank conflicts; involution slot^=(row&7), 16B granules)
//  - bijective XCD-aware workgroup remap (nwg%8==0 for both call sites)
template <int MODE>
__global__ __launch_bounds__(256, 2) void k_gemm(
    const u16* __restrict__ A0, const u16* __restrict__ A1, const u16* __restrict__ A2,
    const u16* __restrict__ B0, const u16* __restrict__ B1, const u16* __restrict__ B2,
    const float* __restrict__ c0, const float* __restrict__ c1, const float* __restrict__ c2,
    void* __restrict__ o0, void* __restrict__ o1, void* __restrict__ o2,
    int Mdim, int Ndim, int Kdim) {
  __shared__ u16 sA[2][128 * 64];
  __shared__ u16 sB[2][128 * 64];

  // XCD-aware remap: XCD j owns a contiguous chunk of the linear wg space
  const int nxy = gridDim.x * gridDim.y;
  const int nwg = nxy * gridDim.z;
  int wg = blockIdx.x + gridDim.x * blockIdx.y + nxy * blockIdx.z;
  wg = (wg & 7) * (nwg >> 3) + (wg >> 3);
  const int z = wg / nxy;
  const int rem = wg % nxy;
  const int by = rem / gridDim.x;
  const int bx = rem % gridDim.x;

  const u16* A  = (z == 0) ? A0 : (z == 1) ? A1 : A2;
  const u16* Bt = (z == 0) ? B0 : (z == 1) ? B1 : B2;
  const float* bias = (z == 0) ? c0 : (z == 1) ? c1 : c2;

  const int tid = threadIdx.x, lane = tid & 63, w = tid >> 6;
  const int wr = w >> 1, wc = w & 1;
  const int m0 = by * 128, n0 = bx * 128;

  // staging: lane -> row (w*32 + i*8 + srow), slot sslot; source col pre-swizzled
  const int srow = lane >> 3, sslot = lane & 7;
  const int scol = (sslot ^ srow) * 8;
  const u16* aBase = A  + (size_t)(m0 + w * 32 + srow) * Kdim + scol;
  const u16* bBase = Bt + (size_t)(n0 + w * 32 + srow) * Kdim + scol;

  const int qlo = lane & 15, g = lane >> 4;
  const int swz = (qlo & 7) << 3;  // u16-index XOR for fragment reads

#define GSTAGE(buf, kt_)                                                         \
  {                                                                              \
    _Pragma("unroll")                                                            \
    for (int i_ = 0; i_ < 4; ++i_) {                                             \
      gload_lds16(aBase + (size_t)i_ * 8 * Kdim + (kt_), &sA[buf][(w * 32 + i_ * 8) * 64]); \
      gload_lds16(bBase + (size_t)i_ * 8 * Kdim + (kt_), &sB[buf][(w * 32 + i_ * 8) * 64]); \
    }                                                                            \
  }

  f32x4 acc[4][4] = {};

  GSTAGE(0, 0);
  __syncthreads();

  int cur = 0;
  for (int kt = 0; kt < Kdim; kt += 64) {
    if (kt + 64 < Kdim) GSTAGE(cur ^ 1, kt + 64);
    __builtin_amdgcn_s_setprio(1);
#pragma unroll
    for (int ks = 0; ks < 2; ++ks) {
      s16x8 af[4], bf[4];
#pragma unroll
      for (int m = 0; m < 4; ++m)
        af[m] = *(const s16x8*)(&sA[cur][(wr * 64 + m * 16 + qlo) * 64 + ((ks * 32 + g * 8) ^ swz)]);
#pragma unroll
      for (int n = 0; n < 4; ++n)
        bf[n] = *(const s16x8*)(&sB[cur][(wc * 64 + n * 16 + qlo) * 64 + ((ks * 32 + g * 8) ^ swz)]);
#pragma unroll
      for (int m = 0; m < 4; ++m)
#pragma unroll
        for (int n = 0; n < 4; ++n)
          acc[m][n] = MFMA16(af[m], bf[n], acc[m][n]);
    }
    __builtin_amdgcn_s_setprio(0);
    __syncthreads();  // drains prefetch vmcnt; separates buffer epochs
    cur ^= 1;
  }
#undef GSTAGE

  if (MODE == 0) {
    u16* out = (u16*)((z == 0) ? o0 : (z == 1) ? o1 : o2);
#pragma unroll
    for (int m = 0; m < 4; ++m) {
      const int gm = m0 + wr * 64 + m * 16 + (g << 2);
#pragma unroll
      for (int n = 0; n < 4; ++n) {
        const int gn = n0 + wc * 64 + n * 16 + qlo;
        const float bv = bias[gn];
        const int hh = gn >> 6, dd = gn & 63;
#pragma unroll
        for (int r = 0; r < 4; ++r) {
          const int row = gm + r;
          const int batch = row >> 10, ss = row & 1023;
          out[(((size_t)(batch * 16 + hh)) * 1024 + ss) * 64 + dd] = f2bf(acc[m][n][r] + bv);
        }
      }
    }
  } else {
    float* out = (float*)o0;
#pragma unroll
    for (int m = 0; m < 4; ++m) {
      const int gm = m0 + wr * 64 + m * 16 + (g << 2);
#pragma unroll
      for (int n = 0; n < 4; ++n) {
        const int gn = n0 + wc * 64 + n * 16 + qlo;
        const float bv = bias[gn];
#pragma unroll
        for (int r = 0; r < 4; ++r)
          out[(size_t)(gm + r) * Ndim + gn] = acc[m][n][r] + bv;
      }
    }
  }
}

// ---------------- V [bh][s][d] -> Vt [bh][d][s] (bf16 tiled transpose) ----------------
__global__ void k_vt(const u16* __restrict__ Vb, u16* __restrict__ Vt) {
  __shared__ u32 t[64][65];
  const int bh = blockIdx.y, s0 = blockIdx.x * 64;
  const int tx = threadIdx.x & 63, ty = threadIdx.x >> 6;
  const u16* src = Vb + (size_t)bh * 65536;
  u16* dst = Vt + (size_t)bh * 65536;
#pragma unroll
  for (int i = 0; i < 16; ++i) {
    const int r = ty * 16 + i;
    t[r][tx] = src[(size_t)(s0 + r) * 64 + tx];
  }
  __syncthreads();
#pragma unroll
  for (int i = 0; i < 16; ++i) {
    const int r = ty * 16 + i;  // d index
    dst[(size_t)r * 1024 + s0 + tx] = (u16)t[tx][r];
  }
}

// ---------------- flash attention v6: R2 softmax + dbuf + XCD swizzle + per-m sP ------
__global__ __launch_bounds__(256, 2) void k_attn(
    const u16* __restrict__ Qb,   // [64 bh][1024][64]
    const u16* __restrict__ Kb,   // [64 bh][1024][64]
    const u16* __restrict__ Vt,   // [64 bh][64][1024]
    const float* __restrict__ tbl,// [16][3969] natural-log-domain bias
    u16* __restrict__ ctx) {      // [4096][1024]
  __shared__ u16 sK[2][64 * 64];    // [kv][d], XOR-swizzled 16B slots
  __shared__ u16 sV[2][64 * 64];    // [d][kv], XOR-swizzled 16B slots
  __shared__ u32 sP[4][2][16][32];  // per-wave, PER-M P bounce, XOR-swizzled dwords
  __shared__ float sTw[2205];       // 35x63 dy-window of the bias table

  // XCD-aware swizzle: all 8 q-blocks of one bh land on one XCD (512 % 8 == 0)
  const int f = blockIdx.x;
  const int nid = (f & 7) * 64 + (f >> 3);
  const int bh = nid >> 3, qblk = nid & 7;
  const int h = bh & 15, b = bh >> 4;
  const int q0 = qblk * 128, yq0 = qblk * 4;

  const int tid = threadIdx.x, lane = tid & 63, w = tid >> 6;
  const int qlo = lane & 15, g = lane >> 4;
  const u16* Qp = Qb + (size_t)bh * (1024 * 64);
  const u16* Kp = Kb + (size_t)bh * (1024 * 64);
  const u16* Vp = Vt + (size_t)bh * (64 * 1024);

  // staging geometry (dst must equal base + lane*16B for global_load_lds)
  const int srow = lane >> 3, sslot = lane & 7;
  const int scol = ((sslot ^ srow) * 8);
  const int swz = (qlo & 7) << 3;

#define STAGE(buf, kv0_)                                                          \
  {                                                                               \
    _Pragma("unroll")                                                             \
    for (int i_ = 0; i_ < 2; ++i_) {                                              \
      const int row_ = w * 16 + i_ * 8 + srow;                                    \
      gload_lds16(Kp + (size_t)((kv0_) + row_) * 64 + scol,                       \
                  &sK[buf][row_ * 64 + sslot * 8]);                               \
      gload_lds16(Vp + (size_t)row_ * 1024 + (kv0_) + scol,                       \
                  &sV[buf][row_ * 64 + sslot * 8]);                               \
    }                                                                             \
  }

  STAGE(0, 0);

  // bias window: rows [yq0, yq0+34] of the 63-wide table -> contiguous 2205 floats
  {
    const float* tblh = tbl + h * 3969 + yq0 * 63;
    for (int i = tid; i < 2205; i += 256) sTw[i] = tblh[i];
  }

  // Q fragments (B-operand: lane holds Q[q=qlo][d = ks*32 + g*8 ..+8])
  s16x8 qf[2][2];
  int W2i[2];
#pragma unroll
  for (int m = 0; m < 2; ++m) {
    const int qi = q0 + w * 32 + m * 16 + qlo;
#pragma unroll
    for (int ks = 0; ks < 2; ++ks)
      qf[m][ks] = *(const s16x8*)(Qp + (size_t)qi * 64 + ks * 32 + g * 8);
    W2i[m] = (w + 31) * 63 + (m * 16 + qlo) + 31 - g * 4;
  }

  f32x4 accO[2][4] = {};
  float mrow[2] = {-3e38f, -3e38f}, lrow[2] = {0.f, 0.f};

  __syncthreads();

  int cur = 0;
  for (int t = 0; t < 16; ++t) {
    const int kv0 = t * 64;
    if (t != 15) STAGE(cur ^ 1, kv0 + 64);

    // QK^T (swapped): lane holds 16 scores (kv = n*16+g*4+r) for q = qlo
    f32x4 sc[2][4] = {};
    __builtin_amdgcn_s_setprio(1);
#pragma unroll
    for (int ks = 0; ks < 2; ++ks) {
      s16x8 kf[4];
#pragma unroll
      for (int n = 0; n < 4; ++n)
        kf[n] = *(const s16x8*)(&sK[cur][(n * 16 + qlo) * 64 + ((ks * 32 + g * 8) ^ swz)]);
#pragma unroll
      for (int m = 0; m < 2; ++m)
#pragma unroll
        for (int n = 0; n < 4; ++n)
          sc[m][n] = MFMA16(kf[n], qf[m][ks], sc[m][n]);
    }
    __builtin_amdgcn_s_setprio(0);

    // R2 online softmax (natural domain, running max, alpha rescale)
    const int bk = (kv0 >> 5) * 63;
#pragma unroll
    for (int m = 0; m < 2; ++m) {
      const int bofs = W2i[m] - bk;
      float sv[16], mx = -3e38f;
#pragma unroll
      for (int n = 0; n < 4; ++n)
#pragma unroll
        for (int r = 0; r < 4; ++r) {
          const float val = sc[m][n][r] * 0.125f +
                            sTw[bofs - ((n >> 1) * 63 + (n & 1) * 16 + r)];
          sv[n * 4 + r] = val;
          mx = fmaxf(mx, val);
        }
      mx = fmaxf(mx, __shfl_xor(mx, 16));
      mx = fmaxf(mx, __shfl_xor(mx, 32));
      const float mold = mrow[m];
      const float mnew = fmaxf(mold, mx);
      const float alpha = __expf(mold - mnew);
      mrow[m] = mnew;
      float p[16], rs = 0.f;
#pragma unroll
      for (int i = 0; i < 16; ++i) { p[i] = __expf(sv[i] - mnew); rs += p[i]; }
      rs += __shfl_xor(rs, 16);
      rs += __shfl_xor(rs, 32);
      lrow[m] = lrow[m] * alpha + rs;
#pragma unroll
      for (int n = 0; n < 4; ++n) accO[m][n] *= alpha;

      // pack P -> wave-private, per-m swizzled LDS (paired b64 writes)
      u32* const prow = &sP[w][m][qlo][0];
      const int dswz = (qlo & 7) << 2;
#pragma unroll
      for (int n = 0; n < 4; ++n) {
        u32x2 pk;
        pk.x = cvt_pk_bf16(p[n * 4 + 0], p[n * 4 + 1]);
        pk.y = cvt_pk_bf16(p[n * 4 + 2], p[n * 4 + 3]);
        *(u32x2*)&prow[(n * 8 + g * 2) ^ dswz] = pk;
      }
    }

    // PV (swapped): accO[m][n] += mfma(V_frag, P_frag); V frags hoisted over m
    __builtin_amdgcn_s_setprio(1);
#pragma unroll
    for (int ks = 0; ks < 2; ++ks) {
      s16x8 av[4];
#pragma unroll
      for (int n = 0; n < 4; ++n)
        av[n] = *(const s16x8*)(&sV[cur][(n * 16 + qlo) * 64 + ((ks * 32 + g * 8) ^ swz)]);
#pragma unroll
      for (int m = 0; m < 2; ++m) {
        const u16* myPm = (const u16*)&sP[w][m][0][0];
        const s16x8 pf = *(const s16x8*)(myPm + qlo * 64 + ((ks * 32 + g * 8) ^ swz));
#pragma unroll
        for (int n = 0; n < 4; ++n)
          accO[m][n] = MFMA16(av[n], pf, accO[m][n]);
      }
    }
    __builtin_amdgcn_s_setprio(0);

    __syncthreads();  // drains prefetch vmcnt + separates buffer epochs
    cur ^= 1;
  }

  // epilogue: lrow already holds the full row sum (reduced in-loop, R2 style)
#pragma unroll
  for (int m = 0; m < 2; ++m) {
    const float inv = 1.0f / lrow[m];
    const int qi = q0 + w * 32 + m * 16 + qlo;
#pragma unroll
    for (int n = 0; n < 4; ++n) {
      ushort4 o4;
      o4.x = f2bf(accO[m][n][0] * inv);
      o4.y = f2bf(accO[m][n][1] * inv);
      o4.z = f2bf(accO[m][n][2] * inv);
      o4.w = f2bf(accO[m][n][3] * inv);
      *(ushort4*)(ctx + ((size_t)(b * 1024 + qi)) * 1024 + h * 64 + n * 16 + g * 4) = o4;
    }
  }
#undef STAGE
}

// ---------------- launch ----------------
extern "C" void kernel_launch(void* const* d_in, const int* in_sizes, int n_in,
                              void* d_out, int out_size, void* d_ws, size_t ws_size,
                              hipStream_t stream) {
  const float* query = (const float*)d_in[0];
  const float* key   = (const float*)d_in[1];
  const float* value = (const float*)d_in[2];
  const float* wq = (const float*)d_in[3];
  const float* bq = (const float*)d_in[4];
  const float* wk = (const float*)d_in[5];
  const float* bk = (const float*)d_in[6];
  const float* wv = (const float*)d_in[7];
  const float* bv = (const float*)d_in[8];
  const float* wo = (const float*)d_in[9];
  const float* bo = (const float*)d_in[10];
  const float* pw0 = (const float*)d_in[11];
  const float* pb0 = (const float*)d_in[12];
  const float* pw1 = (const float*)d_in[13];
  const float* pb1 = (const float*)d_in[14];
  const float* pw2 = (const float*)d_in[15];
  const float* pb2 = (const float*)d_in[16];

  char* ws = (char*)d_ws;
  u16* Xq  = (u16*)(ws + 0);
  u16* Xk  = (u16*)(ws + 8388608);
  u16* Xv  = (u16*)(ws + 16777216);
  u16* Wtq = (u16*)(ws + 25165824);
  u16* Wtk = (u16*)(ws + 27262976);
  u16* Wtv = (u16*)(ws + 29360128);
  u16* Wto = (u16*)(ws + 31457280);
  u16* Qb  = (u16*)(ws + 33554432);
  u16* Kb  = (u16*)(ws + 41943040);
  u16* Vb  = (u16*)(ws + 50331648);
  u16* Vtb = (u16*)(ws + 58720256);
  u16* ctx = (u16*)(ws + 67108864);
  float* tbl = (float*)(ws + 75497472);   // 16*3969*4 = 254016 B

  k_cast<<<dim3(4096, 1, 3), 256, 0, stream>>>(query, key, value, Xq, Xk, Xv);
  k_transpose_w<<<dim3(16, 16, 4), 256, 0, stream>>>(wq, wk, wv, wo, Wtq, Wtk, Wtv, Wto);
  k_posbias<<<dim3(249), 256, 0, stream>>>(pw0, pb0, pw1, pb1, pw2, pb2, tbl);
  k_gemm<0><<<dim3(8, 32, 3), 256, 0, stream>>>(Xq, Xk, Xv, Wtq, Wtk, Wtv,
                                                bq, bk, bv, Qb, Kb, Vb, 4096, 1024, 1024);
  k_vt<<<dim3(16, 64), 256, 0, stream>>>(Vb, Vtb);
  k_attn<<<dim3(512), 256, 0, stream>>>(Qb, Kb, Vtb, tbl, ctx);
  k_gemm<1><<<dim3(8, 32, 1), 256, 0, stream>>>(ctx, ctx, ctx, Wto, Wto, Wto,
                                                bo, bo, bo, d_out, d_out, d_out, 4096, 1024, 1024);
}

// Round 8
// 140.770 us; speedup vs baseline: 1.5533x; 1.0913x over previous
//
#include <hip/hip_runtime.h>
#include <stdint.h>

typedef unsigned short u16;
typedef unsigned int   u32;
typedef __attribute__((ext_vector_type(4))) float f32x4;
typedef __attribute__((ext_vector_type(8))) short s16x8;
typedef __attribute__((ext_vector_type(2))) u32 u32x2;

__device__ __forceinline__ u16 f2bf(float f) {
  u32 u = __builtin_bit_cast(u32, f);
  u = (u + 0x7FFFu + ((u >> 16) & 1u)) >> 16;
  return (u16)u;
}

__device__ __forceinline__ u32 cvt_pk_bf16(float lo, float hi) {
  u32 r;
  asm("v_cvt_pk_bf16_f32 %0, %1, %2" : "=v"(r) : "v"(lo), "v"(hi));
  return r;
}

__device__ __forceinline__ void gload_lds16(const void* g, void* l) {
  __builtin_amdgcn_global_load_lds((const __attribute__((address_space(1))) void*)g,
                                   (__attribute__((address_space(3))) void*)l,
                                   16, 0, 0);
}

#define MFMA16(a, b, c) __builtin_amdgcn_mfma_f32_16x16x32_bf16((a), (b), (c), 0, 0, 0)

// ---------------- cast fp32 -> bf16 (query/key/value) ----------------
__global__ void k_cast(const float* __restrict__ q, const float* __restrict__ k,
                       const float* __restrict__ v,
                       u16* __restrict__ oq, u16* __restrict__ ok, u16* __restrict__ ov) {
  const int z = blockIdx.z;
  const float* src = (z == 0) ? q : (z == 1) ? k : v;
  u16* dst = (z == 0) ? oq : (z == 1) ? ok : ov;
  const int i = (blockIdx.x * 256 + threadIdx.x) * 4;
  const float4 f = *(const float4*)(src + i);
  ushort4 o4;
  o4.x = f2bf(f.x); o4.y = f2bf(f.y); o4.z = f2bf(f.z); o4.w = f2bf(f.w);
  *(ushort4*)(dst + i) = o4;
}

// ---------------- transpose+cast weights: W[K][N] fp32 -> Wt[N][K] bf16 ----------------
__global__ void k_transpose_w(const float* __restrict__ w0, const float* __restrict__ w1,
                              const float* __restrict__ w2, const float* __restrict__ w3,
                              u16* __restrict__ o0, u16* __restrict__ o1,
                              u16* __restrict__ o2, u16* __restrict__ o3) {
  __shared__ float t[64][65];
  const int z = blockIdx.z;
  const float* w = (z == 0) ? w0 : (z == 1) ? w1 : (z == 2) ? w2 : w3;
  u16* o = (z == 0) ? o0 : (z == 1) ? o1 : (z == 2) ? o2 : o3;
  const int k0 = blockIdx.x * 64;
  const int n0 = blockIdx.y * 64;
  const int tx = threadIdx.x & 63, ty = threadIdx.x >> 6;
#pragma unroll
  for (int i = 0; i < 16; ++i) {
    const int r = ty * 16 + i;
    t[r][tx] = w[(size_t)(k0 + r) * 1024 + n0 + tx];
  }
  __syncthreads();
#pragma unroll
  for (int i = 0; i < 16; ++i) {
    const int r = ty * 16 + i;
    o[(size_t)(n0 + r) * 1024 + k0 + tx] = f2bf(t[tx][r]);
  }
}

// ---------------- position-bias MLP v2: 4 rows/block, float4 LDS, split-K layer3 ------
// tbl layout: [16 heads][3969]  (entry p = (dy+31)*63 + (dx+31)); natural-log domain.
// v2 vs v1: 993 blocks (was 249) for occupancy; layer-2 reads h0 as float4 broadcasts
// (4x fewer LDS issue slots); layer-3 split-K over 4 thread-quarters + LDS reduce.
__global__ __launch_bounds__(256) void k_posbias(
    const float* __restrict__ w0, const float* __restrict__ b0,
    const float* __restrict__ w1, const float* __restrict__ b1,
    const float* __restrict__ w2, const float* __restrict__ b2,
    float* __restrict__ tbl) {
  __shared__ float h0[4][264];   // stride 264: float4-aligned, offsets rows by 8 banks
  __shared__ float h1[4][264];
  __shared__ float pr[4][4][16]; // [quarter][row][head] partials
  const int t = threadIdx.x;
  const int p0 = blockIdx.x * 4; // grid 993 -> rows 0..3971 (clamped)
  // layer 1: 2 -> 256
  {
    const float wy = w0[t], wx = w0[256 + t], bb = b0[t];
#pragma unroll
    for (int r = 0; r < 4; ++r) {
      int p = p0 + r; if (p > 3968) p = 3968;
      const float dy = (float)(p / 63 - 31);
      const float dx = (float)(p % 63 - 31);
      const float v = dy * wy + dx * wx + bb;
      h0[r][t] = v > 0.f ? v : 0.01f * v;
    }
  }
  __syncthreads();
  // layer 2: 256 -> 256; thread t owns output column t for all 4 rows
  {
    const float bb = b1[t];
    float a0 = bb, a1 = bb, a2 = bb, a3 = bb;
    for (int k = 0; k < 256; k += 4) {
      const float wA = w1[(k + 0) * 256 + t];
      const float wB = w1[(k + 1) * 256 + t];
      const float wC = w1[(k + 2) * 256 + t];
      const float wD = w1[(k + 3) * 256 + t];
      const float4 x0 = *(const float4*)&h0[0][k];
      const float4 x1 = *(const float4*)&h0[1][k];
      const float4 x2 = *(const float4*)&h0[2][k];
      const float4 x3 = *(const float4*)&h0[3][k];
      a0 += (x0.x * wA + x0.y * wB) + (x0.z * wC + x0.w * wD);
      a1 += (x1.x * wA + x1.y * wB) + (x1.z * wC + x1.w * wD);
      a2 += (x2.x * wA + x2.y * wB) + (x2.z * wC + x2.w * wD);
      a3 += (x3.x * wA + x3.y * wB) + (x3.z * wC + x3.w * wD);
    }
    h1[0][t] = a0 > 0.f ? a0 : 0.01f * a0;
    h1[1][t] = a1 > 0.f ? a1 : 0.01f * a1;
    h1[2][t] = a2 > 0.f ? a2 : 0.01f * a2;
    h1[3][t] = a3 > 0.f ? a3 : 0.01f * a3;
  }
  __syncthreads();
  // layer 3: 256 -> 16; (row, head) split-K across 4 quarters of the block
  {
    const int hh = t & 15, r = (t >> 4) & 3, q = t >> 6;
    const int k0 = q * 64;
    float acc = 0.f;
    for (int k = k0; k < k0 + 64; ++k)
      acc += h1[r][k] * w2[k * 16 + hh];
    pr[q][r][hh] = acc;
  }
  __syncthreads();
  if (t < 64) {
    const int hh = t & 15, r = t >> 4;
    const int p = p0 + r;
    if (p < 3969)
      tbl[hh * 3969 + p] =
          b2[hh] + ((pr[0][r][hh] + pr[1][r][hh]) + (pr[2][r][hh] + pr[3][r][hh]));
  }
}

// ---------------- bf16 GEMM v2: 128x128 tile, BK=64, dbuf prefetch + swizzles ---------
template <int MODE>
__global__ __launch_bounds__(256, 2) void k_gemm(
    const u16* __restrict__ A0, const u16* __restrict__ A1, const u16* __restrict__ A2,
    const u16* __restrict__ B0, const u16* __restrict__ B1, const u16* __restrict__ B2,
    const float* __restrict__ c0, const float* __restrict__ c1, const float* __restrict__ c2,
    void* __restrict__ o0, void* __restrict__ o1, void* __restrict__ o2,
    int Mdim, int Ndim, int Kdim) {
  __shared__ u16 sA[2][128 * 64];
  __shared__ u16 sB[2][128 * 64];

  // XCD-aware remap: XCD j owns a contiguous chunk of the linear wg space
  const int nxy = gridDim.x * gridDim.y;
  const int nwg = nxy * gridDim.z;
  int wg = blockIdx.x + gridDim.x * blockIdx.y + nxy * blockIdx.z;
  wg = (wg & 7) * (nwg >> 3) + (wg >> 3);
  const int z = wg / nxy;
  const int rem = wg % nxy;
  const int by = rem / gridDim.x;
  const int bx = rem % gridDim.x;

  const u16* A  = (z == 0) ? A0 : (z == 1) ? A1 : A2;
  const u16* Bt = (z == 0) ? B0 : (z == 1) ? B1 : B2;
  const float* bias = (z == 0) ? c0 : (z == 1) ? c1 : c2;

  const int tid = threadIdx.x, lane = tid & 63, w = tid >> 6;
  const int wr = w >> 1, wc = w & 1;
  const int m0 = by * 128, n0 = bx * 128;

  // staging: lane -> row (w*32 + i*8 + srow), slot sslot; source col pre-swizzled
  const int srow = lane >> 3, sslot = lane & 7;
  const int scol = (sslot ^ srow) * 8;
  const u16* aBase = A  + (size_t)(m0 + w * 32 + srow) * Kdim + scol;
  const u16* bBase = Bt + (size_t)(n0 + w * 32 + srow) * Kdim + scol;

  const int qlo = lane & 15, g = lane >> 4;
  const int swz = (qlo & 7) << 3;  // u16-index XOR for fragment reads

#define GSTAGE(buf, kt_)                                                         \
  {                                                                              \
    _Pragma("unroll")                                                            \
    for (int i_ = 0; i_ < 4; ++i_) {                                             \
      gload_lds16(aBase + (size_t)i_ * 8 * Kdim + (kt_), &sA[buf][(w * 32 + i_ * 8) * 64]); \
      gload_lds16(bBase + (size_t)i_ * 8 * Kdim + (kt_), &sB[buf][(w * 32 + i_ * 8) * 64]); \
    }                                                                            \
  }

  f32x4 acc[4][4] = {};

  GSTAGE(0, 0);
  __syncthreads();

  int cur = 0;
  for (int kt = 0; kt < Kdim; kt += 64) {
    if (kt + 64 < Kdim) GSTAGE(cur ^ 1, kt + 64);
    __builtin_amdgcn_s_setprio(1);
#pragma unroll
    for (int ks = 0; ks < 2; ++ks) {
      s16x8 af[4], bf[4];
#pragma unroll
      for (int m = 0; m < 4; ++m)
        af[m] = *(const s16x8*)(&sA[cur][(wr * 64 + m * 16 + qlo) * 64 + ((ks * 32 + g * 8) ^ swz)]);
#pragma unroll
      for (int n = 0; n < 4; ++n)
        bf[n] = *(const s16x8*)(&sB[cur][(wc * 64 + n * 16 + qlo) * 64 + ((ks * 32 + g * 8) ^ swz)]);
#pragma unroll
      for (int m = 0; m < 4; ++m)
#pragma unroll
        for (int n = 0; n < 4; ++n)
          acc[m][n] = MFMA16(af[m], bf[n], acc[m][n]);
    }
    __builtin_amdgcn_s_setprio(0);
    __syncthreads();  // drains prefetch vmcnt; separates buffer epochs
    cur ^= 1;
  }
#undef GSTAGE

  if (MODE == 0) {
    u16* out = (u16*)((z == 0) ? o0 : (z == 1) ? o1 : o2);
#pragma unroll
    for (int m = 0; m < 4; ++m) {
      const int gm = m0 + wr * 64 + m * 16 + (g << 2);
#pragma unroll
      for (int n = 0; n < 4; ++n) {
        const int gn = n0 + wc * 64 + n * 16 + qlo;
        const float bv = bias[gn];
        const int hh = gn >> 6, dd = gn & 63;
#pragma unroll
        for (int r = 0; r < 4; ++r) {
          const int row = gm + r;
          const int batch = row >> 10, ss = row & 1023;
          out[(((size_t)(batch * 16 + hh)) * 1024 + ss) * 64 + dd] = f2bf(acc[m][n][r] + bv);
        }
      }
    }
  } else {
    float* out = (float*)o0;
#pragma unroll
    for (int m = 0; m < 4; ++m) {
      const int gm = m0 + wr * 64 + m * 16 + (g << 2);
#pragma unroll
      for (int n = 0; n < 4; ++n) {
        const int gn = n0 + wc * 64 + n * 16 + qlo;
        const float bv = bias[gn];
#pragma unroll
        for (int r = 0; r < 4; ++r)
          out[(size_t)(gm + r) * Ndim + gn] = acc[m][n][r] + bv;
      }
    }
  }
}

// ---------------- V [bh][s][d] -> Vt [bh][d][s] (bf16 tiled transpose) ----------------
__global__ void k_vt(const u16* __restrict__ Vb, u16* __restrict__ Vt) {
  __shared__ u32 t[64][65];
  const int bh = blockIdx.y, s0 = blockIdx.x * 64;
  const int tx = threadIdx.x & 63, ty = threadIdx.x >> 6;
  const u16* src = Vb + (size_t)bh * 65536;
  u16* dst = Vt + (size_t)bh * 65536;
#pragma unroll
  for (int i = 0; i < 16; ++i) {
    const int r = ty * 16 + i;
    t[r][tx] = src[(size_t)(s0 + r) * 64 + tx];
  }
  __syncthreads();
#pragma unroll
  for (int i = 0; i < 16; ++i) {
    const int r = ty * 16 + i;  // d index
    dst[(size_t)r * 1024 + s0 + tx] = (u16)t[tx][r];
  }
}

// ---------------- flash attention v6: R2 softmax + dbuf + XCD swizzle + per-m sP ------
__global__ __launch_bounds__(256, 2) void k_attn(
    const u16* __restrict__ Qb,   // [64 bh][1024][64]
    const u16* __restrict__ Kb,   // [64 bh][1024][64]
    const u16* __restrict__ Vt,   // [64 bh][64][1024]
    const float* __restrict__ tbl,// [16][3969] natural-log-domain bias
    u16* __restrict__ ctx) {      // [4096][1024]
  __shared__ u16 sK[2][64 * 64];    // [kv][d], XOR-swizzled 16B slots
  __shared__ u16 sV[2][64 * 64];    // [d][kv], XOR-swizzled 16B slots
  __shared__ u32 sP[4][2][16][32];  // per-wave, PER-M P bounce, XOR-swizzled dwords
  __shared__ float sTw[2205];       // 35x63 dy-window of the bias table

  // XCD-aware swizzle: all 8 q-blocks of one bh land on one XCD (512 % 8 == 0)
  const int f = blockIdx.x;
  const int nid = (f & 7) * 64 + (f >> 3);
  const int bh = nid >> 3, qblk = nid & 7;
  const int h = bh & 15, b = bh >> 4;
  const int q0 = qblk * 128, yq0 = qblk * 4;

  const int tid = threadIdx.x, lane = tid & 63, w = tid >> 6;
  const int qlo = lane & 15, g = lane >> 4;
  const u16* Qp = Qb + (size_t)bh * (1024 * 64);
  const u16* Kp = Kb + (size_t)bh * (1024 * 64);
  const u16* Vp = Vt + (size_t)bh * (64 * 1024);

  // staging geometry (dst must equal base + lane*16B for global_load_lds)
  const int srow = lane >> 3, sslot = lane & 7;
  const int scol = ((sslot ^ srow) * 8);
  const int swz = (qlo & 7) << 3;

#define STAGE(buf, kv0_)                                                          \
  {                                                                               \
    _Pragma("unroll")                                                             \
    for (int i_ = 0; i_ < 2; ++i_) {                                              \
      const int row_ = w * 16 + i_ * 8 + srow;                                    \
      gload_lds16(Kp + (size_t)((kv0_) + row_) * 64 + scol,                       \
                  &sK[buf][row_ * 64 + sslot * 8]);                               \
      gload_lds16(Vp + (size_t)row_ * 1024 + (kv0_) + scol,                       \
                  &sV[buf][row_ * 64 + sslot * 8]);                               \
    }                                                                             \
  }

  STAGE(0, 0);

  // bias window: rows [yq0, yq0+34] of the 63-wide table -> contiguous 2205 floats
  {
    const float* tblh = tbl + h * 3969 + yq0 * 63;
    for (int i = tid; i < 2205; i += 256) sTw[i] = tblh[i];
  }

  // Q fragments (B-operand: lane holds Q[q=qlo][d = ks*32 + g*8 ..+8])
  s16x8 qf[2][2];
  int W2i[2];
#pragma unroll
  for (int m = 0; m < 2; ++m) {
    const int qi = q0 + w * 32 + m * 16 + qlo;
#pragma unroll
    for (int ks = 0; ks < 2; ++ks)
      qf[m][ks] = *(const s16x8*)(Qp + (size_t)qi * 64 + ks * 32 + g * 8);
    W2i[m] = (w + 31) * 63 + (m * 16 + qlo) + 31 - g * 4;
  }

  f32x4 accO[2][4] = {};
  float mrow[2] = {-3e38f, -3e38f}, lrow[2] = {0.f, 0.f};

  __syncthreads();

  int cur = 0;
  for (int t = 0; t < 16; ++t) {
    const int kv0 = t * 64;
    if (t != 15) STAGE(cur ^ 1, kv0 + 64);

    // QK^T (swapped): lane holds 16 scores (kv = n*16+g*4+r) for q = qlo
    f32x4 sc[2][4] = {};
    __builtin_amdgcn_s_setprio(1);
#pragma unroll
    for (int ks = 0; ks < 2; ++ks) {
      s16x8 kf[4];
#pragma unroll
      for (int n = 0; n < 4; ++n)
        kf[n] = *(const s16x8*)(&sK[cur][(n * 16 + qlo) * 64 + ((ks * 32 + g * 8) ^ swz)]);
#pragma unroll
      for (int m = 0; m < 2; ++m)
#pragma unroll
        for (int n = 0; n < 4; ++n)
          sc[m][n] = MFMA16(kf[n], qf[m][ks], sc[m][n]);
    }
    __builtin_amdgcn_s_setprio(0);

    // R2 online softmax (natural domain, running max, alpha rescale)
    const int bk = (kv0 >> 5) * 63;
#pragma unroll
    for (int m = 0; m < 2; ++m) {
      const int bofs = W2i[m] - bk;
      float sv[16], mx = -3e38f;
#pragma unroll
      for (int n = 0; n < 4; ++n)
#pragma unroll
        for (int r = 0; r < 4; ++r) {
          const float val = sc[m][n][r] * 0.125f +
                            sTw[bofs - ((n >> 1) * 63 + (n & 1) * 16 + r)];
          sv[n * 4 + r] = val;
          mx = fmaxf(mx, val);
        }
      mx = fmaxf(mx, __shfl_xor(mx, 16));
      mx = fmaxf(mx, __shfl_xor(mx, 32));
      const float mold = mrow[m];
      const float mnew = fmaxf(mold, mx);
      const float alpha = __expf(mold - mnew);
      mrow[m] = mnew;
      float p[16], rs = 0.f;
#pragma unroll
      for (int i = 0; i < 16; ++i) { p[i] = __expf(sv[i] - mnew); rs += p[i]; }
      rs += __shfl_xor(rs, 16);
      rs += __shfl_xor(rs, 32);
      lrow[m] = lrow[m] * alpha + rs;
#pragma unroll
      for (int n = 0; n < 4; ++n) accO[m][n] *= alpha;

      // pack P -> wave-private, per-m swizzled LDS (paired b64 writes)
      u32* const prow = &sP[w][m][qlo][0];
      const int dswz = (qlo & 7) << 2;
#pragma unroll
      for (int n = 0; n < 4; ++n) {
        u32x2 pk;
        pk.x = cvt_pk_bf16(p[n * 4 + 0], p[n * 4 + 1]);
        pk.y = cvt_pk_bf16(p[n * 4 + 2], p[n * 4 + 3]);
        *(u32x2*)&prow[(n * 8 + g * 2) ^ dswz] = pk;
      }
    }

    // PV (swapped): accO[m][n] += mfma(V_frag, P_frag); V frags hoisted over m
    __builtin_amdgcn_s_setprio(1);
#pragma unroll
    for (int ks = 0; ks < 2; ++ks) {
      s16x8 av[4];
#pragma unroll
      for (int n = 0; n < 4; ++n)
        av[n] = *(const s16x8*)(&sV[cur][(n * 16 + qlo) * 64 + ((ks * 32 + g * 8) ^ swz)]);
#pragma unroll
      for (int m = 0; m < 2; ++m) {
        const u16* myPm = (const u16*)&sP[w][m][0][0];
        const s16x8 pf = *(const s16x8*)(myPm + qlo * 64 + ((ks * 32 + g * 8) ^ swz));
#pragma unroll
        for (int n = 0; n < 4; ++n)
          accO[m][n] = MFMA16(av[n], pf, accO[m][n]);
      }
    }
    __builtin_amdgcn_s_setprio(0);

    __syncthreads();  // drains prefetch vmcnt + separates buffer epochs
    cur ^= 1;
  }

  // epilogue: lrow already holds the full row sum (reduced in-loop, R2 style)
#pragma unroll
  for (int m = 0; m < 2; ++m) {
    const float inv = 1.0f / lrow[m];
    const int qi = q0 + w * 32 + m * 16 + qlo;
#pragma unroll
    for (int n = 0; n < 4; ++n) {
      ushort4 o4;
      o4.x = f2bf(accO[m][n][0] * inv);
      o4.y = f2bf(accO[m][n][1] * inv);
      o4.z = f2bf(accO[m][n][2] * inv);
      o4.w = f2bf(accO[m][n][3] * inv);
      *(ushort4*)(ctx + ((size_t)(b * 1024 + qi)) * 1024 + h * 64 + n * 16 + g * 4) = o4;
    }
  }
#undef STAGE
}

// ---------------- launch ----------------
extern "C" void kernel_launch(void* const* d_in, const int* in_sizes, int n_in,
                              void* d_out, int out_size, void* d_ws, size_t ws_size,
                              hipStream_t stream) {
  const float* query = (const float*)d_in[0];
  const float* key   = (const float*)d_in[1];
  const float* value = (const float*)d_in[2];
  const float* wq = (const float*)d_in[3];
  const float* bq = (const float*)d_in[4];
  const float* wk = (const float*)d_in[5];
  const float* bk = (const float*)d_in[6];
  const float* wv = (const float*)d_in[7];
  const float* bv = (const float*)d_in[8];
  const float* wo = (const float*)d_in[9];
  const float* bo = (const float*)d_in[10];
  const float* pw0 = (const float*)d_in[11];
  const float* pb0 = (const float*)d_in[12];
  const float* pw1 = (const float*)d_in[13];
  const float* pb1 = (const float*)d_in[14];
  const float* pw2 = (const float*)d_in[15];
  const float* pb2 = (const float*)d_in[16];

  char* ws = (char*)d_ws;
  u16* Xq  = (u16*)(ws + 0);
  u16* Xk  = (u16*)(ws + 8388608);
  u16* Xv  = (u16*)(ws + 16777216);
  u16* Wtq = (u16*)(ws + 25165824);
  u16* Wtk = (u16*)(ws + 27262976);
  u16* Wtv = (u16*)(ws + 29360128);
  u16* Wto = (u16*)(ws + 31457280);
  u16* Qb  = (u16*)(ws + 33554432);
  u16* Kb  = (u16*)(ws + 41943040);
  u16* Vb  = (u16*)(ws + 50331648);
  u16* Vtb = (u16*)(ws + 58720256);
  u16* ctx = (u16*)(ws + 67108864);
  float* tbl = (float*)(ws + 75497472);   // 16*3969*4 = 254016 B

  k_cast<<<dim3(4096, 1, 3), 256, 0, stream>>>(query, key, value, Xq, Xk, Xv);
  k_transpose_w<<<dim3(16, 16, 4), 256, 0, stream>>>(wq, wk, wv, wo, Wtq, Wtk, Wtv, Wto);
  k_posbias<<<dim3(993), 256, 0, stream>>>(pw0, pb0, pw1, pb1, pw2, pb2, tbl);
  k_gemm<0><<<dim3(8, 32, 3), 256, 0, stream>>>(Xq, Xk, Xv, Wtq, Wtk, Wtv,
                                                bq, bk, bv, Qb, Kb, Vb, 4096, 1024, 1024);
  k_vt<<<dim3(16, 64), 256, 0, stream>>>(Vb, Vtb);
  k_attn<<<dim3(512), 256, 0, stream>>>(Qb, Kb, Vtb, tbl, ctx);
  k_gemm<1><<<dim3(8, 32, 1), 256, 0, stream>>>(ctx, ctx, ctx, Wto, Wto, Wto,
                                                bo, bo, bo, d_out, d_out, d_out, 4096, 1024, 1024);
}